// Round 12
// baseline (911.154 us; speedup 1.0000x reference)
//
#include <hip/hip_runtime.h>
#include <hip/hip_bf16.h>
#include <math.h>

// N=100000, D=128, H=8, HID=256, QK=64, V=64, PSI_HID=256, OUT=128
#define NPTS 100000
#define NPAD 100352           // 784*128 = 32*3136
#define NHALF 50176           // 16*3136 = 49*1024
#define RPB 3136              // rows per gemm block
#define HIDST 40              // per-wave hid row stride (80 B)
#define KVST 264              // k_kv LDS row stride
#define CDST 68               // k_cd cat/hid row stride (136 B, <=2-way banks)

typedef __bf16 bf16x8 __attribute__((ext_vector_type(8)));
typedef __bf16 bf16x4 __attribute__((ext_vector_type(4)));
typedef float f32x4 __attribute__((ext_vector_type(4)));

#define MFMA16(a,b,c) __builtin_amdgcn_mfma_f32_16x16x32_bf16((a),(b),(c),0,0,0)
#define SW(row) (((row)&7)<<3)

// ---------- prep: weights cast/transpose ----------
__global__ void k_prep_w(const float* __restrict__ Wq0, const float* __restrict__ Wk0,
                         const float* __restrict__ Wv0, const float* __restrict__ Wq1,
                         const float* __restrict__ Wk1, const float* __restrict__ Wv1,
                         const float* __restrict__ Wp0, const float* __restrict__ Wp1,
                         __bf16* __restrict__ W0t, __bf16* __restrict__ W1t,
                         __bf16* __restrict__ Wp0t, __bf16* __restrict__ Wp1t) {
  for (int i = blockIdx.x * 256 + threadIdx.x; i < 1343488; i += gridDim.x * 256) {
    if (i < 786432) {                      // W0t [24][256 hid][128 d]
      int g = i >> 15, j = i & 32767;
      int mat = g >> 3, h = g & 7, mcol = j >> 7, k = j & 127;
      const float* src = (mat == 0) ? Wq0 : (mat == 1) ? Wk0 : Wv0;
      W0t[i] = (__bf16)src[h * 32768 + k * 256 + mcol];
    } else if (i < 1179648) {              // W1t [24][64 o][256 hid]
      int t = i - 786432;
      int g = t >> 14, j = t & 16383;
      int mat = g >> 3, h = g & 7, ocol = j >> 8, k = j & 255;
      const float* src = (mat == 0) ? Wq1 : (mat == 1) ? Wk1 : Wv1;
      W1t[t] = (__bf16)src[h * 16384 + k * 64 + ocol];
    } else if (i < 1310720) {              // Wp0t [256][512]
      int t = i - 1179648;
      int col = t >> 9, k = t & 511;
      Wp0t[t] = (__bf16)Wp0[k * 256 + col];
    } else {                               // Wp1t [128][256]
      int t = i - 1310720;
      int col = t >> 8, k = t & 255;
      Wp1t[t] = (__bf16)Wp1[k * 128 + col];
    }
  }
}

// ---------- load 64 X rows (f32 -> bf16 regs), zero beyond NPTS ----------
__device__ __forceinline__ void load_ax(const float* __restrict__ coords,
                                        int base, int l15, int lg, bf16x8 (&ax)[4][4]) {
  #pragma unroll
  for (int jt = 0; jt < 4; ++jt) {
    int row = base + jt * 16 + l15;
    bool ok = row < NPTS;
    #pragma unroll
    for (int ks = 0; ks < 4; ++ks) {
      bf16x8 v = {};
      if (ok) {
        const float4* p4 = (const float4*)(coords + (size_t)row * 128 + ks * 32 + lg * 8);
        float4 f0 = p4[0], f1 = p4[1];
        v[0] = (__bf16)f0.x; v[1] = (__bf16)f0.y; v[2] = (__bf16)f0.z; v[3] = (__bf16)f0.w;
        v[4] = (__bf16)f1.x; v[5] = (__bf16)f1.y; v[6] = (__bf16)f1.z; v[7] = (__bf16)f1.w;
      }
      ax[jt][ks] = v;
    }
  }
}

// ---------- q GEMM: one head per 32-block group, 3136 rows/block ----------
__global__ __launch_bounds__(512, 2) void k_qgemm(
    const float* __restrict__ coords, const float* __restrict__ mask,
    const __bf16* __restrict__ W0t, const __bf16* __restrict__ W1t,
    const float* __restrict__ bq0, const float* __restrict__ bq1,
    __bf16* __restrict__ qk_ws)
{
  __shared__ __bf16 sW0[32768];            // 64 KB [256 hid][128 d] swizzled
  __shared__ __bf16 sW1[16384];            // 32 KB [64 o][256 hid] swizzled
  __shared__ __bf16 sHid[8 * 64 * HIDST];  // 40 KB per-wave [64 row][32 col]

  const int tid = threadIdx.x, w = tid >> 6, lane = tid & 63;
  const int l15 = lane & 15, lg = lane >> 4;
  const int h = blockIdx.x >> 5, rb = blockIdx.x & 31;

  const __bf16* w0 = W0t + (size_t)h * 32768;
  const __bf16* w1 = W1t + (size_t)h * 16384;
  #pragma unroll
  for (int i = 0; i < 8; ++i) {
    int u = tid + i * 512, row = u >> 4, k8 = (u & 15) << 3;
    *(bf16x8*)&sW0[(row * 128 + k8) ^ SW(row)] = *(const bf16x8*)(w0 + row * 128 + k8);
  }
  #pragma unroll
  for (int i = 0; i < 4; ++i) {
    int u = tid + i * 512, o = u >> 5, k8 = (u & 31) << 3;
    *(bf16x8*)&sW1[(o * 256 + k8) ^ SW(o)] = *(const bf16x8*)(w1 + o * 256 + k8);
  }
  __syncthreads();

  __bf16* myHid = sHid + w * (64 * HIDST);

  #pragma unroll 1
  for (int it = 0; it < 7; ++it) {
    const int roff = it * 512 + w * 64;
    if (roff >= RPB) break;
    const int base = rb * RPB + roff;

    bf16x8 ax[4][4];
    load_ax(coords, base, l15, lg, ax);

    f32x4 acc2[16];
    #pragma unroll
    for (int i = 0; i < 16; ++i) acc2[i] = f32x4{0.f, 0.f, 0.f, 0.f};

    #pragma unroll 1
    for (int c = 0; c < 8; ++c) {
      f32x4 a1[2][4] = {};
      #pragma unroll
      for (int ks = 0; ks < 4; ++ks) {
        bf16x8 wa[2];
        #pragma unroll
        for (int fi = 0; fi < 2; ++fi) {
          int hl = c * 32 + fi * 16 + l15;
          wa[fi] = *(const bf16x8*)&sW0[(hl * 128 + ks * 32 + lg * 8) ^ SW(hl)];
        }
        #pragma unroll
        for (int fi = 0; fi < 2; ++fi)
          #pragma unroll
          for (int jt = 0; jt < 4; ++jt)
            a1[fi][jt] = MFMA16(wa[fi], ax[jt][ks], a1[fi][jt]);
      }
      #pragma unroll
      for (int fi = 0; fi < 2; ++fi) {
        f32x4 b0v = *(const f32x4*)&bq0[h * 256 + c * 32 + fi * 16 + lg * 4];
        #pragma unroll
        for (int jt = 0; jt < 4; ++jt) {
          bf16x4 hv;
          #pragma unroll
          for (int r = 0; r < 4; ++r) {
            float v = a1[fi][jt][r] + b0v[r];
            hv[r] = (__bf16)(v > 0.f ? v : 0.f);
          }
          *(bf16x4*)&myHid[(jt * 16 + l15) * HIDST + fi * 16 + lg * 4] = hv;
        }
      }
      bf16x8 hb[4], wf[4];
      #pragma unroll
      for (int jt = 0; jt < 4; ++jt)
        hb[jt] = *(const bf16x8*)&myHid[(jt * 16 + l15) * HIDST + lg * 8];
      #pragma unroll
      for (int f = 0; f < 4; ++f) {
        int o = f * 16 + l15;
        wf[f] = *(const bf16x8*)&sW1[(o * 256 + c * 32 + lg * 8) ^ SW(o)];
      }
      #pragma unroll
      for (int ft = 0; ft < 4; ++ft)
        #pragma unroll
        for (int jt = 0; jt < 4; ++jt)
          acc2[ft * 4 + jt] = MFMA16(wf[ft], hb[jt], acc2[ft * 4 + jt]);   // swapped
    }

    float mq[4];
    #pragma unroll
    for (int jt = 0; jt < 4; ++jt) {
      int rq = base + jt * 16 + l15;
      mq[jt] = (rq < NPTS) ? mask[rq] : 0.f;
    }
    #pragma unroll
    for (int ft = 0; ft < 4; ++ft) {
      f32x4 b1v = *(const f32x4*)&bq1[h * 64 + ft * 16 + lg * 4];
      #pragma unroll
      for (int jt = 0; jt < 4; ++jt) {
        bf16x4 qv;
        f32x4 a = acc2[ft * 4 + jt];
        #pragma unroll
        for (int r = 0; r < 4; ++r) {
          float v = (a[r] + b1v[r]) * mq[jt];
          qv[r] = (__bf16)(v > 0.f ? v + 1.f : __expf(v));
        }
        *(bf16x4*)(qk_ws + ((size_t)h * NPAD + base + jt * 16 + l15) * 64 + ft * 16 + lg * 4) = qv;
      }
    }
  }
}

// ---------- k/v GEMM over one half of N (50176 rows) ----------
__global__ __launch_bounds__(512, 2) void k_kvgemm(
    const float* __restrict__ coords, const float* __restrict__ mask,
    const __bf16* __restrict__ W0t, const __bf16* __restrict__ W1t,
    const float* __restrict__ bk0, const float* __restrict__ bk1,
    const float* __restrict__ bv0, const float* __restrict__ bv1,
    __bf16* __restrict__ kkTh, __bf16* __restrict__ vTh, int rowOff)
{
  __shared__ __bf16 sW0[32768];
  __shared__ __bf16 sW1[16384];
  __shared__ __bf16 sHid[8 * 64 * HIDST];

  const int tid = threadIdx.x, w = tid >> 6, lane = tid & 63;
  const int l15 = lane & 15, lg = lane >> 4;
  const int mh2 = blockIdx.x >> 4, rb = blockIdx.x & 15;
  const int m2 = mh2 >> 3, h = mh2 & 7;          // m2: 0=k, 1=v

  const __bf16* w0 = W0t + (size_t)((m2 + 1) * 8 + h) * 32768;
  const __bf16* w1 = W1t + (size_t)((m2 + 1) * 8 + h) * 16384;
  #pragma unroll
  for (int i = 0; i < 8; ++i) {
    int u = tid + i * 512, row = u >> 4, k8 = (u & 15) << 3;
    *(bf16x8*)&sW0[(row * 128 + k8) ^ SW(row)] = *(const bf16x8*)(w0 + row * 128 + k8);
  }
  #pragma unroll
  for (int i = 0; i < 4; ++i) {
    int u = tid + i * 512, o = u >> 5, k8 = (u & 31) << 3;
    *(bf16x8*)&sW1[(o * 256 + k8) ^ SW(o)] = *(const bf16x8*)(w1 + o * 256 + k8);
  }
  __syncthreads();

  const float* b0 = m2 ? bv0 : bk0;
  const float* b1 = m2 ? bv1 : bk1;
  __bf16* dstT = m2 ? vTh : kkTh;
  __bf16* myHid = sHid + w * (64 * HIDST);

  #pragma unroll 1
  for (int it = 0; it < 7; ++it) {
    const int roff = it * 512 + w * 64;
    if (roff >= RPB) break;
    const int lbase = rb * RPB + roff;          // half-local
    const int gbase = rowOff + lbase;           // global

    bf16x8 ax[4][4];
    load_ax(coords, gbase, l15, lg, ax);

    f32x4 acc2[16];
    #pragma unroll
    for (int i = 0; i < 16; ++i) acc2[i] = f32x4{0.f, 0.f, 0.f, 0.f};

    #pragma unroll 1
    for (int c = 0; c < 8; ++c) {
      f32x4 a1[2][4] = {};
      #pragma unroll
      for (int ks = 0; ks < 4; ++ks) {
        bf16x8 wa[2];
        #pragma unroll
        for (int fi = 0; fi < 2; ++fi) {
          int hl = c * 32 + fi * 16 + l15;
          wa[fi] = *(const bf16x8*)&sW0[(hl * 128 + ks * 32 + lg * 8) ^ SW(hl)];
        }
        #pragma unroll
        for (int fi = 0; fi < 2; ++fi)
          #pragma unroll
          for (int jt = 0; jt < 4; ++jt)
            a1[fi][jt] = MFMA16(wa[fi], ax[jt][ks], a1[fi][jt]);
      }
      #pragma unroll
      for (int fi = 0; fi < 2; ++fi) {
        f32x4 b0v = *(const f32x4*)&b0[h * 256 + c * 32 + fi * 16 + lg * 4];
        #pragma unroll
        for (int jt = 0; jt < 4; ++jt) {
          bf16x4 hv;
          #pragma unroll
          for (int r = 0; r < 4; ++r) {
            float v = a1[fi][jt][r] + b0v[r];
            hv[r] = (__bf16)(v > 0.f ? v : 0.f);
          }
          *(bf16x4*)&myHid[(jt * 16 + l15) * HIDST + fi * 16 + lg * 4] = hv;
        }
      }
      bf16x8 hb[4], wf[4];
      #pragma unroll
      for (int jt = 0; jt < 4; ++jt)
        hb[jt] = *(const bf16x8*)&myHid[(jt * 16 + l15) * HIDST + lg * 8];
      #pragma unroll
      for (int f = 0; f < 4; ++f) {
        int o = f * 16 + l15;
        wf[f] = *(const bf16x8*)&sW1[(o * 256 + c * 32 + lg * 8) ^ SW(o)];
      }
      #pragma unroll
      for (int jt = 0; jt < 4; ++jt)
        #pragma unroll
        for (int f = 0; f < 4; ++f)
          acc2[jt * 4 + f] = MFMA16(hb[jt], wf[f], acc2[jt * 4 + f]);      // normal
    }

    f32x4 mv[4];
    #pragma unroll
    for (int jt = 0; jt < 4; ++jt) {
      int rv = gbase + jt * 16 + lg * 4;
      #pragma unroll
      for (int r = 0; r < 4; ++r) mv[jt][r] = (rv + r < NPTS) ? mask[rv + r] : 0.f;
    }
    if (m2 == 0) {
      #pragma unroll
      for (int f = 0; f < 4; ++f) {
        float b1s = b1[h * 64 + f * 16 + l15];
        #pragma unroll
        for (int jt = 0; jt < 4; ++jt) {
          bf16x4 k4;
          f32x4 a = acc2[jt * 4 + f];
          #pragma unroll
          for (int r = 0; r < 4; ++r) {
            int row = gbase + jt * 16 + lg * 4 + r;
            float v = (a[r] + b1s) * mv[jt][r];
            k4[r] = (__bf16)((row < NPTS) ? (v > 0.f ? v + 1.f : __expf(v)) : 0.f);
          }
          *(bf16x4*)(dstT + (size_t)(h * 64 + f * 16 + l15) * NHALF + lbase + jt * 16 + lg * 4) = k4;
        }
      }
    } else {
      #pragma unroll
      for (int f = 0; f < 4; ++f) {
        float b1s = b1[h * 64 + f * 16 + l15];
        #pragma unroll
        for (int jt = 0; jt < 4; ++jt) {
          bf16x4 v4;
          f32x4 a = acc2[jt * 4 + f];
          #pragma unroll
          for (int r = 0; r < 4; ++r)
            v4[r] = (__bf16)((a[r] + b1s) * mv[jt][r]);
          *(bf16x4*)(dstT + (size_t)(h * 64 + f * 16 + l15) * NHALF + lbase + jt * 16 + lg * 4) = v4;
        }
      }
    }
  }
}

// ---------- kv = kkT @ v over one half (split-K 1024 rows), sumk via ones-MFMA ----------
__global__ __launch_bounds__(256) void k_kv(
    const __bf16* __restrict__ kkTh, const __bf16* __restrict__ vTh,
    float* __restrict__ parts_kv, float* __restrict__ parts_sk, int poff)
{
  __shared__ __bf16 sA[64 * KVST];
  __shared__ __bf16 sB[64 * KVST];
  const int tid = threadIdx.x, w = tid >> 6, lane = tid & 63;
  const int l15 = lane & 15, lg = lane >> 4;
  const int sp = blockIdx.x, h = blockIdx.y;
  const int kbase0 = sp * 1024;

  bf16x8 ones;
  #pragma unroll
  for (int e = 0; e < 8; ++e) ones[e] = (__bf16)1.0f;

  f32x4 akv[4] = {};
  f32x4 ask = {};

  #pragma unroll 1
  for (int ch = 0; ch < 4; ++ch) {
    int kb = kbase0 + ch * 256;
    __syncthreads();
    #pragma unroll
    for (int i = 0; i < 8; ++i) {
      int u = tid + i * 256, row = u >> 5, k8 = (u & 31) << 3;
      *(bf16x8*)&sA[row * KVST + k8] = *(const bf16x8*)(kkTh + (size_t)(h * 64 + row) * NHALF + kb + k8);
    }
    #pragma unroll
    for (int i = 0; i < 8; ++i) {
      int u = tid + i * 256, row = u >> 5, k8 = (u & 31) << 3;
      *(bf16x8*)&sB[row * KVST + k8] = *(const bf16x8*)(vTh + (size_t)(h * 64 + row) * NHALF + kb + k8);
    }
    __syncthreads();
    #pragma unroll
    for (int ks = 0; ks < 8; ++ks) {
      bf16x8 a = *(const bf16x8*)&sA[(w * 16 + l15) * KVST + ks * 32 + lg * 8];
      #pragma unroll
      for (int fj = 0; fj < 4; ++fj) {
        bf16x8 b = *(const bf16x8*)&sB[(fj * 16 + l15) * KVST + ks * 32 + lg * 8];
        akv[fj] = MFMA16(a, b, akv[fj]);
      }
      ask = MFMA16(a, ones, ask);
    }
  }
  float* dkv = parts_kv + ((size_t)h * 98 + poff + sp) * 4096;
  #pragma unroll
  for (int fj = 0; fj < 4; ++fj)
    #pragma unroll
    for (int r = 0; r < 4; ++r)
      dkv[(size_t)(w * 16 + lg * 4 + r) * 64 + fj * 16 + l15] = akv[fj][r];
  if (l15 == 0) {
    float* dsk = parts_sk + ((size_t)h * 98 + poff + sp) * 64;
    #pragma unroll
    for (int r = 0; r < 4; ++r) dsk[w * 16 + lg * 4 + r] = ask[r];
  }
}

// ---------- reduce parts -> kvTe bf16 [8][j][kq], sumk f32 [512] ----------
__global__ void k_kvt(const float* __restrict__ parts_kv, const float* __restrict__ parts_sk,
                      __bf16* __restrict__ kvTe, float* __restrict__ sumk) {
  int i = blockIdx.x * 256 + threadIdx.x;
  if (i < 32768) {
    int h = i >> 12, rem = i & 4095;
    float s = 0.f;
    for (int sp = 0; sp < 98; ++sp) s += parts_kv[((size_t)h * 98 + sp) * 4096 + rem];
    int kq = rem >> 6, j = rem & 63;
    kvTe[((size_t)h * 64 + j) * 64 + kq] = (__bf16)s;
  } else if (i < 33280) {
    int t = i - 32768;
    int h = t >> 6, c = t & 63;
    float s = 0.f;
    for (int sp = 0; sp < 98; ++sp) s += parts_sk[((size_t)h * 98 + sp) * 64 + c];
    sumk[t] = s;
  }
}

// ---------- attention normalize + psi MLP ----------
// Wp0 chunk LDS-staged per head (direct, no reg prefetch -> no spill);
// cat + hid chunks wave-private; chunked layer2; LDS 68 KB -> 2 blocks/CU.
__global__ __launch_bounds__(512, 2) void k_cd(
    const float* __restrict__ mask, const __bf16* __restrict__ qk_ws,
    const __bf16* __restrict__ kvTe, const float* __restrict__ sumk,
    const __bf16* __restrict__ Wp0t, const __bf16* __restrict__ Wp1t,
    const float* __restrict__ bp0, const float* __restrict__ bp1,
    float* __restrict__ out)
{
  __shared__ __bf16 sWp0c[16384];          // 32 KB: [256 col][64 k] swizzled
  __shared__ __bf16 sCat[8 * 16 * CDST];   // 17 KB: per-wave cat [16][64]
  __shared__ __bf16 sHc[8 * 16 * CDST];    // 17 KB: per-wave hid chunk [16][64]
  __shared__ float sSumk[512];             //  2 KB

  const int tid = threadIdx.x, w = tid >> 6, lane = tid & 63, l15 = lane & 15, lg = lane >> 4;
  const int rbase = blockIdx.x * 128 + w * 16;
  __bf16* myCat = sCat + w * (16 * CDST);
  __bf16* myHc = sHc + w * (16 * CDST);

  sSumk[tid] = sumk[tid];

  // direct Wp0 chunk staging (transient registers only)
  auto STAGEW = [&](int h) {
    #pragma unroll
    for (int i = 0; i < 4; ++i) {
      int u = tid + i * 512;
      int col = u >> 3, koff = (u & 7) << 3;
      *(bf16x8*)&sWp0c[(col * 64 + koff) ^ SW(col)] =
          *(const bf16x8*)(Wp0t + (size_t)col * 512 + h * 64 + koff);
    }
  };

  STAGEW(0);
  __syncthreads();          // covers sSumk + first sWp0c

  f32x4 acc1[16] = {};
  #pragma unroll 1
  for (int h = 0; h < 8; ++h) {
    bf16x8 axq[2];
    #pragma unroll
    for (int ks = 0; ks < 2; ++ks)
      axq[ks] = *(const bf16x8*)(qk_ws + ((size_t)h * NPAD + rbase + l15) * 64 + ks * 32 + lg * 8);
    // num = qk @ kv
    f32x4 accn[4] = {};
    #pragma unroll
    for (int ks = 0; ks < 2; ++ks)
      #pragma unroll
      for (int f = 0; f < 4; ++f) {
        bf16x8 bv = *(const bf16x8*)(kvTe + ((size_t)h * 64 + f * 16 + l15) * 64 + ks * 32 + lg * 8);
        accn[f] = MFMA16(axq[ks], bv, accn[f]);
      }
    // den: per-lane partial + xor-reduce
    float p = 0.f;
    #pragma unroll
    for (int ks = 0; ks < 2; ++ks)
      #pragma unroll
      for (int e = 0; e < 8; ++e)
        p += (float)axq[ks][e] * sSumk[h * 64 + ks * 32 + lg * 8 + e];
    p += __shfl_xor(p, 16);
    p += __shfl_xor(p, 32);
    float dinv[4];
    #pragma unroll
    for (int r = 0; r < 4; ++r) {
      float d = __shfl(p, (lane & 48) + ((lane >> 4) << 2) + r);
      d = (d == 0.f) ? 1e-6f : d;
      dinv[r] = 1.f / d;
    }
    // cat chunk -> wave-private LDS
    #pragma unroll
    for (int f = 0; f < 4; ++f)
      #pragma unroll
      for (int r = 0; r < 4; ++r)
        myCat[(lg * 4 + r) * CDST + f * 16 + l15] = (__bf16)(accn[f][r] * dinv[r]);
    // psi layer1 partial: A from myCat, B from LDS-staged Wp0 chunk
    #pragma unroll
    for (int ks2 = 0; ks2 < 2; ++ks2) {
      bf16x8 aC = *(const bf16x8*)&myCat[l15 * CDST + ks2 * 32 + lg * 8];
      #pragma unroll
      for (int f = 0; f < 16; ++f) {
        bf16x8 bw = *(const bf16x8*)&sWp0c[((f * 16 + l15) * 64 + ks2 * 32 + lg * 8) ^ SW(l15)];
        acc1[f] = MFMA16(aC, bw, acc1[f]);
      }
    }
    if (h + 1 < 8) {
      __syncthreads();      // all waves done reading sWp0c for head h
      STAGEW(h + 1);
      __syncthreads();      // ready for head h+1
    }
  }
  // layer2 in 4 K-chunks of 64 (hid chunk wave-private, barrier-free)
  f32x4 acc2[8] = {};
  #pragma unroll 1
  for (int c = 0; c < 4; ++c) {
    #pragma unroll
    for (int fi = 0; fi < 4; ++fi) {
      float bias = bp0[(c * 4 + fi) * 16 + l15];
      #pragma unroll
      for (int r = 0; r < 4; ++r) {
        float val = acc1[c * 4 + fi][r] + bias;
        val = val > 0.f ? val : 0.f;
        myHc[(lg * 4 + r) * CDST + fi * 16 + l15] = (__bf16)val;
      }
    }
    #pragma unroll
    for (int ks2 = 0; ks2 < 2; ++ks2) {
      bf16x8 aH = *(const bf16x8*)&myHc[l15 * CDST + ks2 * 32 + lg * 8];
      #pragma unroll
      for (int f = 0; f < 8; ++f) {
        bf16x8 bw = *(const bf16x8*)(Wp1t + (size_t)(f * 16 + l15) * 256 + c * 64 + ks2 * 32 + lg * 8);
        acc2[f] = MFMA16(aH, bw, acc2[f]);
      }
    }
  }
  float mvr[4];
  #pragma unroll
  for (int r = 0; r < 4; ++r) {
    int grow = rbase + lg * 4 + r;
    mvr[r] = (grow < NPTS) ? mask[grow] : 0.f;
  }
  #pragma unroll
  for (int f = 0; f < 8; ++f) {
    int col = f * 16 + l15;
    float bias = bp1[col];
    #pragma unroll
    for (int r = 0; r < 4; ++r) {
      int grow = rbase + lg * 4 + r;
      if (grow < NPTS) out[(size_t)grow * 128 + col] = (acc2[f][r] + bias) * mvr[r];
    }
  }
}

extern "C" void kernel_launch(void* const* d_in, const int* in_sizes, int n_in,
                              void* d_out, int out_size, void* d_ws, size_t ws_size,
                              hipStream_t stream) {
  const float* coords = (const float*)d_in[0];
  const float* mask   = (const float*)d_in[1];
  const float* Wq0 = (const float*)d_in[2];
  const float* bq0 = (const float*)d_in[3];
  const float* Wq1 = (const float*)d_in[4];
  const float* bq1 = (const float*)d_in[5];
  const float* Wk0 = (const float*)d_in[6];
  const float* bk0 = (const float*)d_in[7];
  const float* Wk1 = (const float*)d_in[8];
  const float* bk1 = (const float*)d_in[9];
  const float* Wv0 = (const float*)d_in[10];
  const float* bv0 = (const float*)d_in[11];
  const float* Wv1 = (const float*)d_in[12];
  const float* bv1 = (const float*)d_in[13];
  const float* Wp0 = (const float*)d_in[14];
  const float* bp0 = (const float*)d_in[15];
  const float* Wp1 = (const float*)d_in[16];
  const float* bp1 = (const float*)d_in[17];
  float* out = (float*)d_out;

  // workspace: region0 (102.8 MB) time-shared between {kkTh|vTh} and qk_ws.
  char* p = (char*)d_ws;
  __bf16* region0  = (__bf16*)p; p += (size_t)8 * NPAD * 64 * 2;    // 102,760,448
  __bf16* qk_ws    = region0;
  __bf16* kkTh     = region0;
  __bf16* vTh      = region0 + (size_t)8 * 64 * NHALF;
  __bf16* W0t      = (__bf16*)p; p += (size_t)24 * 32768 * 2;       //   1,572,864
  __bf16* W1t      = (__bf16*)p; p += (size_t)24 * 16384 * 2;       //     786,432
  __bf16* Wp0t     = (__bf16*)p; p += (size_t)256 * 512 * 2;        //     262,144
  __bf16* Wp1t     = (__bf16*)p; p += (size_t)128 * 256 * 2;        //      65,536
  float*  parts_kv = (float*)p;  p += (size_t)8 * 98 * 4096 * 4;    //  12,845,056
  float*  parts_sk = (float*)p;  p += (size_t)8 * 98 * 64 * 4;      //     200,704
  float*  sumk     = (float*)p;  p += (size_t)512 * 4;              //       2,048
  __bf16* kvTe     = (__bf16*)p; p += (size_t)8 * 64 * 64 * 2;      //      65,536

  k_prep_w<<<1024, 256, 0, stream>>>(Wq0, Wk0, Wv0, Wq1, Wk1, Wv1, Wp0, Wp1,
                                     W0t, W1t, Wp0t, Wp1t);
  k_kvgemm<<<256, 512, 0, stream>>>(coords, mask, W0t, W1t, bk0, bk1, bv0, bv1,
                                    kkTh, vTh, 0);
  k_kv<<<dim3(49, 8), 256, 0, stream>>>(kkTh, vTh, parts_kv, parts_sk, 0);
  k_kvgemm<<<256, 512, 0, stream>>>(coords, mask, W0t, W1t, bk0, bk1, bv0, bv1,
                                    kkTh, vTh, NHALF);
  k_kv<<<dim3(49, 8), 256, 0, stream>>>(kkTh, vTh, parts_kv, parts_sk, 49);
  k_qgemm<<<256, 512, 0, stream>>>(coords, mask, W0t, W1t, bq0, bq1, qk_ws);
  k_kvt<<<130, 256, 0, stream>>>(parts_kv, parts_sk, kvTe, sumk);
  k_cd<<<784, 512, 0, stream>>>(mask, qk_ws, kvTe, sumk, Wp0t, Wp1t, bp0, bp1, out);
}

// Round 13
// 657.033 us; speedup vs baseline: 1.3868x; 1.3868x over previous
//
#include <hip/hip_runtime.h>
#include <hip/hip_bf16.h>
#include <math.h>

// N=100000, D=128, H=8, HID=256, QK=64, V=64, PSI_HID=256, OUT=128
#define NPTS 100000
#define NPAD 100352           // 784*128 = 32*3136
#define NHALF 50176           // 16*3136 = 49*1024
#define RPB 3136              // rows per gemm block
#define HIDST 40              // per-wave hid row stride (80 B)
#define KVST 264              // k_kv LDS row stride
#define CDST 68               // k_cd cat/hid row stride (136 B, <=2-way banks)

typedef __bf16 bf16x8 __attribute__((ext_vector_type(8)));
typedef __bf16 bf16x4 __attribute__((ext_vector_type(4)));
typedef float f32x4 __attribute__((ext_vector_type(4)));

#define MFMA16(a,b,c) __builtin_amdgcn_mfma_f32_16x16x32_bf16((a),(b),(c),0,0,0)
#define SW(row) (((row)&7)<<3)

// ---------- prep: weights cast/transpose ----------
__global__ void k_prep_w(const float* __restrict__ Wq0, const float* __restrict__ Wk0,
                         const float* __restrict__ Wv0, const float* __restrict__ Wq1,
                         const float* __restrict__ Wk1, const float* __restrict__ Wv1,
                         const float* __restrict__ Wp0, const float* __restrict__ Wp1,
                         __bf16* __restrict__ W0t, __bf16* __restrict__ W1t,
                         __bf16* __restrict__ Wp0t, __bf16* __restrict__ Wp1t) {
  for (int i = blockIdx.x * 256 + threadIdx.x; i < 1343488; i += gridDim.x * 256) {
    if (i < 786432) {                      // W0t [24][256 hid][128 d]
      int g = i >> 15, j = i & 32767;
      int mat = g >> 3, h = g & 7, mcol = j >> 7, k = j & 127;
      const float* src = (mat == 0) ? Wq0 : (mat == 1) ? Wk0 : Wv0;
      W0t[i] = (__bf16)src[h * 32768 + k * 256 + mcol];
    } else if (i < 1179648) {              // W1t [24][64 o][256 hid]
      int t = i - 786432;
      int g = t >> 14, j = t & 16383;
      int mat = g >> 3, h = g & 7, ocol = j >> 8, k = j & 255;
      const float* src = (mat == 0) ? Wq1 : (mat == 1) ? Wk1 : Wv1;
      W1t[t] = (__bf16)src[h * 16384 + k * 64 + ocol];
    } else if (i < 1310720) {              // Wp0t [256][512]
      int t = i - 1179648;
      int col = t >> 9, k = t & 511;
      Wp0t[t] = (__bf16)Wp0[k * 256 + col];
    } else {                               // Wp1t [128][256]
      int t = i - 1310720;
      int col = t >> 8, k = t & 255;
      Wp1t[t] = (__bf16)Wp1[k * 128 + col];
    }
  }
}

// ---------- load 64 X rows (f32 -> bf16 regs), zero beyond NPTS ----------
__device__ __forceinline__ void load_ax(const float* __restrict__ coords,
                                        int base, int l15, int lg, bf16x8 (&ax)[4][4]) {
  #pragma unroll
  for (int jt = 0; jt < 4; ++jt) {
    int row = base + jt * 16 + l15;
    bool ok = row < NPTS;
    #pragma unroll
    for (int ks = 0; ks < 4; ++ks) {
      bf16x8 v = {};
      if (ok) {
        const float4* p4 = (const float4*)(coords + (size_t)row * 128 + ks * 32 + lg * 8);
        float4 f0 = p4[0], f1 = p4[1];
        v[0] = (__bf16)f0.x; v[1] = (__bf16)f0.y; v[2] = (__bf16)f0.z; v[3] = (__bf16)f0.w;
        v[4] = (__bf16)f1.x; v[5] = (__bf16)f1.y; v[6] = (__bf16)f1.z; v[7] = (__bf16)f1.w;
      }
      ax[jt][ks] = v;
    }
  }
}

// ---------- q GEMM: one head per 32-block group, 3136 rows/block ----------
__global__ __launch_bounds__(512, 2) void k_qgemm(
    const float* __restrict__ coords, const float* __restrict__ mask,
    const __bf16* __restrict__ W0t, const __bf16* __restrict__ W1t,
    const float* __restrict__ bq0, const float* __restrict__ bq1,
    __bf16* __restrict__ qk_ws)
{
  __shared__ __bf16 sW0[32768];            // 64 KB [256 hid][128 d] swizzled
  __shared__ __bf16 sW1[16384];            // 32 KB [64 o][256 hid] swizzled
  __shared__ __bf16 sHid[8 * 64 * HIDST];  // 40 KB per-wave [64 row][32 col]

  const int tid = threadIdx.x, w = tid >> 6, lane = tid & 63;
  const int l15 = lane & 15, lg = lane >> 4;
  const int h = blockIdx.x >> 5, rb = blockIdx.x & 31;

  const __bf16* w0 = W0t + (size_t)h * 32768;
  const __bf16* w1 = W1t + (size_t)h * 16384;
  #pragma unroll
  for (int i = 0; i < 8; ++i) {
    int u = tid + i * 512, row = u >> 4, k8 = (u & 15) << 3;
    *(bf16x8*)&sW0[(row * 128 + k8) ^ SW(row)] = *(const bf16x8*)(w0 + row * 128 + k8);
  }
  #pragma unroll
  for (int i = 0; i < 4; ++i) {
    int u = tid + i * 512, o = u >> 5, k8 = (u & 31) << 3;
    *(bf16x8*)&sW1[(o * 256 + k8) ^ SW(o)] = *(const bf16x8*)(w1 + o * 256 + k8);
  }
  __syncthreads();

  __bf16* myHid = sHid + w * (64 * HIDST);

  #pragma unroll 1
  for (int it = 0; it < 7; ++it) {
    const int roff = it * 512 + w * 64;
    if (roff >= RPB) break;
    const int base = rb * RPB + roff;

    bf16x8 ax[4][4];
    load_ax(coords, base, l15, lg, ax);

    f32x4 acc2[16];
    #pragma unroll
    for (int i = 0; i < 16; ++i) acc2[i] = f32x4{0.f, 0.f, 0.f, 0.f};

    #pragma unroll 1
    for (int c = 0; c < 8; ++c) {
      f32x4 a1[2][4] = {};
      #pragma unroll
      for (int ks = 0; ks < 4; ++ks) {
        bf16x8 wa[2];
        #pragma unroll
        for (int fi = 0; fi < 2; ++fi) {
          int hl = c * 32 + fi * 16 + l15;
          wa[fi] = *(const bf16x8*)&sW0[(hl * 128 + ks * 32 + lg * 8) ^ SW(hl)];
        }
        #pragma unroll
        for (int fi = 0; fi < 2; ++fi)
          #pragma unroll
          for (int jt = 0; jt < 4; ++jt)
            a1[fi][jt] = MFMA16(wa[fi], ax[jt][ks], a1[fi][jt]);
      }
      #pragma unroll
      for (int fi = 0; fi < 2; ++fi) {
        f32x4 b0v = *(const f32x4*)&bq0[h * 256 + c * 32 + fi * 16 + lg * 4];
        #pragma unroll
        for (int jt = 0; jt < 4; ++jt) {
          bf16x4 hv;
          #pragma unroll
          for (int r = 0; r < 4; ++r) {
            float v = a1[fi][jt][r] + b0v[r];
            hv[r] = (__bf16)(v > 0.f ? v : 0.f);
          }
          *(bf16x4*)&myHid[(jt * 16 + l15) * HIDST + fi * 16 + lg * 4] = hv;
        }
      }
      bf16x8 hb[4], wf[4];
      #pragma unroll
      for (int jt = 0; jt < 4; ++jt)
        hb[jt] = *(const bf16x8*)&myHid[(jt * 16 + l15) * HIDST + lg * 8];
      #pragma unroll
      for (int f = 0; f < 4; ++f) {
        int o = f * 16 + l15;
        wf[f] = *(const bf16x8*)&sW1[(o * 256 + c * 32 + lg * 8) ^ SW(o)];
      }
      #pragma unroll
      for (int ft = 0; ft < 4; ++ft)
        #pragma unroll
        for (int jt = 0; jt < 4; ++jt)
          acc2[ft * 4 + jt] = MFMA16(wf[ft], hb[jt], acc2[ft * 4 + jt]);   // swapped
    }

    float mq[4];
    #pragma unroll
    for (int jt = 0; jt < 4; ++jt) {
      int rq = base + jt * 16 + l15;
      mq[jt] = (rq < NPTS) ? mask[rq] : 0.f;
    }
    #pragma unroll
    for (int ft = 0; ft < 4; ++ft) {
      f32x4 b1v = *(const f32x4*)&bq1[h * 64 + ft * 16 + lg * 4];
      #pragma unroll
      for (int jt = 0; jt < 4; ++jt) {
        bf16x4 qv;
        f32x4 a = acc2[ft * 4 + jt];
        #pragma unroll
        for (int r = 0; r < 4; ++r) {
          float v = (a[r] + b1v[r]) * mq[jt];
          qv[r] = (__bf16)(v > 0.f ? v + 1.f : __expf(v));
        }
        *(bf16x4*)(qk_ws + ((size_t)h * NPAD + base + jt * 16 + l15) * 64 + ft * 16 + lg * 4) = qv;
      }
    }
  }
}

// ---------- k/v GEMM over one half of N (50176 rows) ----------
__global__ __launch_bounds__(512, 2) void k_kvgemm(
    const float* __restrict__ coords, const float* __restrict__ mask,
    const __bf16* __restrict__ W0t, const __bf16* __restrict__ W1t,
    const float* __restrict__ bk0, const float* __restrict__ bk1,
    const float* __restrict__ bv0, const float* __restrict__ bv1,
    __bf16* __restrict__ kkTh, __bf16* __restrict__ vTh, int rowOff)
{
  __shared__ __bf16 sW0[32768];
  __shared__ __bf16 sW1[16384];
  __shared__ __bf16 sHid[8 * 64 * HIDST];

  const int tid = threadIdx.x, w = tid >> 6, lane = tid & 63;
  const int l15 = lane & 15, lg = lane >> 4;
  const int mh2 = blockIdx.x >> 4, rb = blockIdx.x & 15;
  const int m2 = mh2 >> 3, h = mh2 & 7;          // m2: 0=k, 1=v

  const __bf16* w0 = W0t + (size_t)((m2 + 1) * 8 + h) * 32768;
  const __bf16* w1 = W1t + (size_t)((m2 + 1) * 8 + h) * 16384;
  #pragma unroll
  for (int i = 0; i < 8; ++i) {
    int u = tid + i * 512, row = u >> 4, k8 = (u & 15) << 3;
    *(bf16x8*)&sW0[(row * 128 + k8) ^ SW(row)] = *(const bf16x8*)(w0 + row * 128 + k8);
  }
  #pragma unroll
  for (int i = 0; i < 4; ++i) {
    int u = tid + i * 512, o = u >> 5, k8 = (u & 31) << 3;
    *(bf16x8*)&sW1[(o * 256 + k8) ^ SW(o)] = *(const bf16x8*)(w1 + o * 256 + k8);
  }
  __syncthreads();

  const float* b0 = m2 ? bv0 : bk0;
  const float* b1 = m2 ? bv1 : bk1;
  __bf16* dstT = m2 ? vTh : kkTh;
  __bf16* myHid = sHid + w * (64 * HIDST);

  #pragma unroll 1
  for (int it = 0; it < 7; ++it) {
    const int roff = it * 512 + w * 64;
    if (roff >= RPB) break;
    const int lbase = rb * RPB + roff;          // half-local
    const int gbase = rowOff + lbase;           // global

    bf16x8 ax[4][4];
    load_ax(coords, gbase, l15, lg, ax);

    f32x4 acc2[16];
    #pragma unroll
    for (int i = 0; i < 16; ++i) acc2[i] = f32x4{0.f, 0.f, 0.f, 0.f};

    #pragma unroll 1
    for (int c = 0; c < 8; ++c) {
      f32x4 a1[2][4] = {};
      #pragma unroll
      for (int ks = 0; ks < 4; ++ks) {
        bf16x8 wa[2];
        #pragma unroll
        for (int fi = 0; fi < 2; ++fi) {
          int hl = c * 32 + fi * 16 + l15;
          wa[fi] = *(const bf16x8*)&sW0[(hl * 128 + ks * 32 + lg * 8) ^ SW(hl)];
        }
        #pragma unroll
        for (int fi = 0; fi < 2; ++fi)
          #pragma unroll
          for (int jt = 0; jt < 4; ++jt)
            a1[fi][jt] = MFMA16(wa[fi], ax[jt][ks], a1[fi][jt]);
      }
      #pragma unroll
      for (int fi = 0; fi < 2; ++fi) {
        f32x4 b0v = *(const f32x4*)&b0[h * 256 + c * 32 + fi * 16 + lg * 4];
        #pragma unroll
        for (int jt = 0; jt < 4; ++jt) {
          bf16x4 hv;
          #pragma unroll
          for (int r = 0; r < 4; ++r) {
            float v = a1[fi][jt][r] + b0v[r];
            hv[r] = (__bf16)(v > 0.f ? v : 0.f);
          }
          *(bf16x4*)&myHid[(jt * 16 + l15) * HIDST + fi * 16 + lg * 4] = hv;
        }
      }
      bf16x8 hb[4], wf[4];
      #pragma unroll
      for (int jt = 0; jt < 4; ++jt)
        hb[jt] = *(const bf16x8*)&myHid[(jt * 16 + l15) * HIDST + lg * 8];
      #pragma unroll
      for (int f = 0; f < 4; ++f) {
        int o = f * 16 + l15;
        wf[f] = *(const bf16x8*)&sW1[(o * 256 + c * 32 + lg * 8) ^ SW(o)];
      }
      #pragma unroll
      for (int jt = 0; jt < 4; ++jt)
        #pragma unroll
        for (int f = 0; f < 4; ++f)
          acc2[jt * 4 + f] = MFMA16(hb[jt], wf[f], acc2[jt * 4 + f]);      // normal
    }

    f32x4 mv[4];
    #pragma unroll
    for (int jt = 0; jt < 4; ++jt) {
      int rv = gbase + jt * 16 + lg * 4;
      #pragma unroll
      for (int r = 0; r < 4; ++r) mv[jt][r] = (rv + r < NPTS) ? mask[rv + r] : 0.f;
    }
    if (m2 == 0) {
      #pragma unroll
      for (int f = 0; f < 4; ++f) {
        float b1s = b1[h * 64 + f * 16 + l15];
        #pragma unroll
        for (int jt = 0; jt < 4; ++jt) {
          bf16x4 k4;
          f32x4 a = acc2[jt * 4 + f];
          #pragma unroll
          for (int r = 0; r < 4; ++r) {
            int row = gbase + jt * 16 + lg * 4 + r;
            float v = (a[r] + b1s) * mv[jt][r];
            k4[r] = (__bf16)((row < NPTS) ? (v > 0.f ? v + 1.f : __expf(v)) : 0.f);
          }
          *(bf16x4*)(dstT + (size_t)(h * 64 + f * 16 + l15) * NHALF + lbase + jt * 16 + lg * 4) = k4;
        }
      }
    } else {
      #pragma unroll
      for (int f = 0; f < 4; ++f) {
        float b1s = b1[h * 64 + f * 16 + l15];
        #pragma unroll
        for (int jt = 0; jt < 4; ++jt) {
          bf16x4 v4;
          f32x4 a = acc2[jt * 4 + f];
          #pragma unroll
          for (int r = 0; r < 4; ++r)
            v4[r] = (__bf16)((a[r] + b1s) * mv[jt][r]);
          *(bf16x4*)(dstT + (size_t)(h * 64 + f * 16 + l15) * NHALF + lbase + jt * 16 + lg * 4) = v4;
        }
      }
    }
  }
}

// ---------- kv = kkT @ v over one half (split-K 1024 rows), sumk via ones-MFMA ----------
__global__ __launch_bounds__(256) void k_kv(
    const __bf16* __restrict__ kkTh, const __bf16* __restrict__ vTh,
    float* __restrict__ parts_kv, float* __restrict__ parts_sk, int poff)
{
  __shared__ __bf16 sA[64 * KVST];
  __shared__ __bf16 sB[64 * KVST];
  const int tid = threadIdx.x, w = tid >> 6, lane = tid & 63;
  const int l15 = lane & 15, lg = lane >> 4;
  const int sp = blockIdx.x, h = blockIdx.y;
  const int kbase0 = sp * 1024;

  bf16x8 ones;
  #pragma unroll
  for (int e = 0; e < 8; ++e) ones[e] = (__bf16)1.0f;

  f32x4 akv[4] = {};
  f32x4 ask = {};

  #pragma unroll 1
  for (int ch = 0; ch < 4; ++ch) {
    int kb = kbase0 + ch * 256;
    __syncthreads();
    #pragma unroll
    for (int i = 0; i < 8; ++i) {
      int u = tid + i * 256, row = u >> 5, k8 = (u & 31) << 3;
      *(bf16x8*)&sA[row * KVST + k8] = *(const bf16x8*)(kkTh + (size_t)(h * 64 + row) * NHALF + kb + k8);
    }
    #pragma unroll
    for (int i = 0; i < 8; ++i) {
      int u = tid + i * 256, row = u >> 5, k8 = (u & 31) << 3;
      *(bf16x8*)&sB[row * KVST + k8] = *(const bf16x8*)(vTh + (size_t)(h * 64 + row) * NHALF + kb + k8);
    }
    __syncthreads();
    #pragma unroll
    for (int ks = 0; ks < 8; ++ks) {
      bf16x8 a = *(const bf16x8*)&sA[(w * 16 + l15) * KVST + ks * 32 + lg * 8];
      #pragma unroll
      for (int fj = 0; fj < 4; ++fj) {
        bf16x8 b = *(const bf16x8*)&sB[(fj * 16 + l15) * KVST + ks * 32 + lg * 8];
        akv[fj] = MFMA16(a, b, akv[fj]);
      }
      ask = MFMA16(a, ones, ask);
    }
  }
  float* dkv = parts_kv + ((size_t)h * 98 + poff + sp) * 4096;
  #pragma unroll
  for (int fj = 0; fj < 4; ++fj)
    #pragma unroll
    for (int r = 0; r < 4; ++r)
      dkv[(size_t)(w * 16 + lg * 4 + r) * 64 + fj * 16 + l15] = akv[fj][r];
  if (l15 == 0) {
    float* dsk = parts_sk + ((size_t)h * 98 + poff + sp) * 64;
    #pragma unroll
    for (int r = 0; r < 4; ++r) dsk[w * 16 + lg * 4 + r] = ask[r];
  }
}

// ---------- reduce parts -> kvTe bf16 [8][j][kq], sumk f32 [512] ----------
__global__ void k_kvt(const float* __restrict__ parts_kv, const float* __restrict__ parts_sk,
                      __bf16* __restrict__ kvTe, float* __restrict__ sumk) {
  int i = blockIdx.x * 256 + threadIdx.x;
  if (i < 32768) {
    int h = i >> 12, rem = i & 4095;
    float s = 0.f;
    for (int sp = 0; sp < 98; ++sp) s += parts_kv[((size_t)h * 98 + sp) * 4096 + rem];
    int kq = rem >> 6, j = rem & 63;
    kvTe[((size_t)h * 64 + j) * 64 + kq] = (__bf16)s;
  } else if (i < 33280) {
    int t = i - 32768;
    int h = t >> 6, c = t & 63;
    float s = 0.f;
    for (int sp = 0; sp < 98; ++sp) s += parts_sk[((size_t)h * 98 + sp) * 64 + c];
    sumk[t] = s;
  }
}

// ---------- attention normalize + psi MLP ----------
// Wp0 chunk LDS-staged per head; cat + hid wave-private; FULLY-UNROLLED
// layer2 chunks (static acc1 indices -> registers, rule #20); 68 KB LDS,
// launch_bounds(512,4) -> 128-reg budget, 2 blocks/CU.
__global__ __launch_bounds__(512, 4) void k_cd(
    const float* __restrict__ mask, const __bf16* __restrict__ qk_ws,
    const __bf16* __restrict__ kvTe, const float* __restrict__ sumk,
    const __bf16* __restrict__ Wp0t, const __bf16* __restrict__ Wp1t,
    const float* __restrict__ bp0, const float* __restrict__ bp1,
    float* __restrict__ out)
{
  __shared__ __bf16 sWp0c[16384];          // 32 KB: [256 col][64 k] swizzled
  __shared__ __bf16 sCat[8 * 16 * CDST];   // 17 KB: per-wave cat [16][64]
  __shared__ __bf16 sHc[8 * 16 * CDST];    // 17 KB: per-wave hid chunk [16][64]
  __shared__ float sSumk[512];             //  2 KB

  const int tid = threadIdx.x, w = tid >> 6, lane = tid & 63, l15 = lane & 15, lg = lane >> 4;
  const int rbase = blockIdx.x * 128 + w * 16;
  __bf16* myCat = sCat + w * (16 * CDST);
  __bf16* myHc = sHc + w * (16 * CDST);

  sSumk[tid] = sumk[tid];

  // direct Wp0 chunk staging (transient registers only)
  auto STAGEW = [&](int h) {
    #pragma unroll
    for (int i = 0; i < 4; ++i) {
      int u = tid + i * 512;
      int col = u >> 3, koff = (u & 7) << 3;
      *(bf16x8*)&sWp0c[(col * 64 + koff) ^ SW(col)] =
          *(const bf16x8*)(Wp0t + (size_t)col * 512 + h * 64 + koff);
    }
  };

  STAGEW(0);
  __syncthreads();          // covers sSumk + first sWp0c

  f32x4 acc1[16] = {};
  #pragma unroll 1
  for (int h = 0; h < 8; ++h) {
    bf16x8 axq[2];
    #pragma unroll
    for (int ks = 0; ks < 2; ++ks)
      axq[ks] = *(const bf16x8*)(qk_ws + ((size_t)h * NPAD + rbase + l15) * 64 + ks * 32 + lg * 8);
    // num = qk @ kv
    f32x4 accn[4] = {};
    #pragma unroll
    for (int ks = 0; ks < 2; ++ks)
      #pragma unroll
      for (int f = 0; f < 4; ++f) {
        bf16x8 bv = *(const bf16x8*)(kvTe + ((size_t)h * 64 + f * 16 + l15) * 64 + ks * 32 + lg * 8);
        accn[f] = MFMA16(axq[ks], bv, accn[f]);
      }
    // den: per-lane partial + xor-reduce
    float p = 0.f;
    #pragma unroll
    for (int ks = 0; ks < 2; ++ks)
      #pragma unroll
      for (int e = 0; e < 8; ++e)
        p += (float)axq[ks][e] * sSumk[h * 64 + ks * 32 + lg * 8 + e];
    p += __shfl_xor(p, 16);
    p += __shfl_xor(p, 32);
    float dinv[4];
    #pragma unroll
    for (int r = 0; r < 4; ++r) {
      float d = __shfl(p, (lane & 48) + ((lane >> 4) << 2) + r);
      d = (d == 0.f) ? 1e-6f : d;
      dinv[r] = 1.f / d;
    }
    // cat chunk -> wave-private LDS
    #pragma unroll
    for (int f = 0; f < 4; ++f)
      #pragma unroll
      for (int r = 0; r < 4; ++r)
        myCat[(lg * 4 + r) * CDST + f * 16 + l15] = (__bf16)(accn[f][r] * dinv[r]);
    // psi layer1 partial: A from myCat, B from LDS-staged Wp0 chunk
    #pragma unroll
    for (int ks2 = 0; ks2 < 2; ++ks2) {
      bf16x8 aC = *(const bf16x8*)&myCat[l15 * CDST + ks2 * 32 + lg * 8];
      #pragma unroll
      for (int f = 0; f < 16; ++f) {
        bf16x8 bw = *(const bf16x8*)&sWp0c[((f * 16 + l15) * 64 + ks2 * 32 + lg * 8) ^ SW(l15)];
        acc1[f] = MFMA16(aC, bw, acc1[f]);
      }
    }
    if (h + 1 < 8) {
      __syncthreads();      // all waves done reading sWp0c for head h
      STAGEW(h + 1);
      __syncthreads();      // ready for head h+1
    }
  }
  // layer2 in 4 K-chunks of 64 — FULLY UNROLLED so acc1 indices are static
  f32x4 acc2[8] = {};
  #pragma unroll
  for (int c = 0; c < 4; ++c) {
    #pragma unroll
    for (int fi = 0; fi < 4; ++fi) {
      float bias = bp0[(c * 4 + fi) * 16 + l15];
      #pragma unroll
      for (int r = 0; r < 4; ++r) {
        float val = acc1[c * 4 + fi][r] + bias;
        val = val > 0.f ? val : 0.f;
        myHc[(lg * 4 + r) * CDST + fi * 16 + l15] = (__bf16)val;
      }
    }
    #pragma unroll
    for (int ks2 = 0; ks2 < 2; ++ks2) {
      bf16x8 aH = *(const bf16x8*)&myHc[l15 * CDST + ks2 * 32 + lg * 8];
      #pragma unroll
      for (int f = 0; f < 8; ++f) {
        bf16x8 bw = *(const bf16x8*)(Wp1t + (size_t)(f * 16 + l15) * 256 + c * 64 + ks2 * 32 + lg * 8);
        acc2[f] = MFMA16(aH, bw, acc2[f]);
      }
    }
  }
  float mvr[4];
  #pragma unroll
  for (int r = 0; r < 4; ++r) {
    int grow = rbase + lg * 4 + r;
    mvr[r] = (grow < NPTS) ? mask[grow] : 0.f;
  }
  #pragma unroll
  for (int f = 0; f < 8; ++f) {
    int col = f * 16 + l15;
    float bias = bp1[col];
    #pragma unroll
    for (int r = 0; r < 4; ++r) {
      int grow = rbase + lg * 4 + r;
      if (grow < NPTS) out[(size_t)grow * 128 + col] = (acc2[f][r] + bias) * mvr[r];
    }
  }
}

extern "C" void kernel_launch(void* const* d_in, const int* in_sizes, int n_in,
                              void* d_out, int out_size, void* d_ws, size_t ws_size,
                              hipStream_t stream) {
  const float* coords = (const float*)d_in[0];
  const float* mask   = (const float*)d_in[1];
  const float* Wq0 = (const float*)d_in[2];
  const float* bq0 = (const float*)d_in[3];
  const float* Wq1 = (const float*)d_in[4];
  const float* bq1 = (const float*)d_in[5];
  const float* Wk0 = (const float*)d_in[6];
  const float* bk0 = (const float*)d_in[7];
  const float* Wk1 = (const float*)d_in[8];
  const float* bk1 = (const float*)d_in[9];
  const float* Wv0 = (const float*)d_in[10];
  const float* bv0 = (const float*)d_in[11];
  const float* Wv1 = (const float*)d_in[12];
  const float* bv1 = (const float*)d_in[13];
  const float* Wp0 = (const float*)d_in[14];
  const float* bp0 = (const float*)d_in[15];
  const float* Wp1 = (const float*)d_in[16];
  const float* bp1 = (const float*)d_in[17];
  float* out = (float*)d_out;

  // workspace: region0 (102.8 MB) time-shared between {kkTh|vTh} and qk_ws.
  char* p = (char*)d_ws;
  __bf16* region0  = (__bf16*)p; p += (size_t)8 * NPAD * 64 * 2;    // 102,760,448
  __bf16* qk_ws    = region0;
  __bf16* kkTh     = region0;
  __bf16* vTh      = region0 + (size_t)8 * 64 * NHALF;
  __bf16* W0t      = (__bf16*)p; p += (size_t)24 * 32768 * 2;       //   1,572,864
  __bf16* W1t      = (__bf16*)p; p += (size_t)24 * 16384 * 2;       //     786,432
  __bf16* Wp0t     = (__bf16*)p; p += (size_t)256 * 512 * 2;        //     262,144
  __bf16* Wp1t     = (__bf16*)p; p += (size_t)128 * 256 * 2;        //      65,536
  float*  parts_kv = (float*)p;  p += (size_t)8 * 98 * 4096 * 4;    //  12,845,056
  float*  parts_sk = (float*)p;  p += (size_t)8 * 98 * 64 * 4;      //     200,704
  float*  sumk     = (float*)p;  p += (size_t)512 * 4;              //       2,048
  __bf16* kvTe     = (__bf16*)p; p += (size_t)8 * 64 * 64 * 2;      //      65,536

  k_prep_w<<<1024, 256, 0, stream>>>(Wq0, Wk0, Wv0, Wq1, Wk1, Wv1, Wp0, Wp1,
                                     W0t, W1t, Wp0t, Wp1t);
  k_kvgemm<<<256, 512, 0, stream>>>(coords, mask, W0t, W1t, bk0, bk1, bv0, bv1,
                                    kkTh, vTh, 0);
  k_kv<<<dim3(49, 8), 256, 0, stream>>>(kkTh, vTh, parts_kv, parts_sk, 0);
  k_kvgemm<<<256, 512, 0, stream>>>(coords, mask, W0t, W1t, bk0, bk1, bv0, bv1,
                                    kkTh, vTh, NHALF);
  k_kv<<<dim3(49, 8), 256, 0, stream>>>(kkTh, vTh, parts_kv, parts_sk, 49);
  k_qgemm<<<256, 512, 0, stream>>>(coords, mask, W0t, W1t, bq0, bq1, qk_ws);
  k_kvt<<<130, 256, 0, stream>>>(parts_kv, parts_sk, kvTe, sumk);
  k_cd<<<784, 512, 0, stream>>>(mask, qk_ws, kvTe, sumk, Wp0t, Wp1t, bp0, bp1, out);
}

// Round 14
// 638.333 us; speedup vs baseline: 1.4274x; 1.0293x over previous
//
#include <hip/hip_runtime.h>
#include <hip/hip_bf16.h>
#include <math.h>

// N=100000, D=128, H=8, HID=256, QK=64, V=64, PSI_HID=256, OUT=128
#define NPTS 100000
#define NPAD 100352           // 784*128 = 32*3136 = 1568*64
#define NHALF 50176           // 16*3136 = 49*1024
#define RPB 3136              // rows per gemm block
#define HIDST 40              // per-wave hid row stride (80 B)
#define KVST 264              // k_kv LDS row stride
#define CDST 68               // k_cd cat/hid row stride (136 B, <=2-way banks)

typedef __bf16 bf16x8 __attribute__((ext_vector_type(8)));
typedef __bf16 bf16x4 __attribute__((ext_vector_type(4)));
typedef float f32x4 __attribute__((ext_vector_type(4)));

#define MFMA16(a,b,c) __builtin_amdgcn_mfma_f32_16x16x32_bf16((a),(b),(c),0,0,0)
#define SW(row) (((row)&7)<<3)

// ---------- prep: weights cast/transpose ----------
__global__ void k_prep_w(const float* __restrict__ Wq0, const float* __restrict__ Wk0,
                         const float* __restrict__ Wv0, const float* __restrict__ Wq1,
                         const float* __restrict__ Wk1, const float* __restrict__ Wv1,
                         const float* __restrict__ Wp0, const float* __restrict__ Wp1,
                         __bf16* __restrict__ W0t, __bf16* __restrict__ W1t,
                         __bf16* __restrict__ Wp0t, __bf16* __restrict__ Wp1t) {
  for (int i = blockIdx.x * 256 + threadIdx.x; i < 1343488; i += gridDim.x * 256) {
    if (i < 786432) {                      // W0t [24][256 hid][128 d]
      int g = i >> 15, j = i & 32767;
      int mat = g >> 3, h = g & 7, mcol = j >> 7, k = j & 127;
      const float* src = (mat == 0) ? Wq0 : (mat == 1) ? Wk0 : Wv0;
      W0t[i] = (__bf16)src[h * 32768 + k * 256 + mcol];
    } else if (i < 1179648) {              // W1t [24][64 o][256 hid]
      int t = i - 786432;
      int g = t >> 14, j = t & 16383;
      int mat = g >> 3, h = g & 7, ocol = j >> 8, k = j & 255;
      const float* src = (mat == 0) ? Wq1 : (mat == 1) ? Wk1 : Wv1;
      W1t[t] = (__bf16)src[h * 16384 + k * 64 + ocol];
    } else if (i < 1310720) {              // Wp0t [256][512]
      int t = i - 1179648;
      int col = t >> 9, k = t & 511;
      Wp0t[t] = (__bf16)Wp0[k * 256 + col];
    } else {                               // Wp1t [128][256]
      int t = i - 1310720;
      int col = t >> 8, k = t & 255;
      Wp1t[t] = (__bf16)Wp1[k * 128 + col];
    }
  }
}

// ---------- load 64 X rows (f32 -> bf16 regs), zero beyond NPTS ----------
__device__ __forceinline__ void load_ax(const float* __restrict__ coords,
                                        int base, int l15, int lg, bf16x8 (&ax)[4][4]) {
  #pragma unroll
  for (int jt = 0; jt < 4; ++jt) {
    int row = base + jt * 16 + l15;
    bool ok = row < NPTS;
    #pragma unroll
    for (int ks = 0; ks < 4; ++ks) {
      bf16x8 v = {};
      if (ok) {
        const float4* p4 = (const float4*)(coords + (size_t)row * 128 + ks * 32 + lg * 8);
        float4 f0 = p4[0], f1 = p4[1];
        v[0] = (__bf16)f0.x; v[1] = (__bf16)f0.y; v[2] = (__bf16)f0.z; v[3] = (__bf16)f0.w;
        v[4] = (__bf16)f1.x; v[5] = (__bf16)f1.y; v[6] = (__bf16)f1.z; v[7] = (__bf16)f1.w;
      }
      ax[jt][ks] = v;
    }
  }
}

// ---------- q GEMM: one head per 32-block group, 3136 rows/block ----------
__global__ __launch_bounds__(512, 2) void k_qgemm(
    const float* __restrict__ coords, const float* __restrict__ mask,
    const __bf16* __restrict__ W0t, const __bf16* __restrict__ W1t,
    const float* __restrict__ bq0, const float* __restrict__ bq1,
    __bf16* __restrict__ qk_ws)
{
  __shared__ __bf16 sW0[32768];            // 64 KB [256 hid][128 d] swizzled
  __shared__ __bf16 sW1[16384];            // 32 KB [64 o][256 hid] swizzled
  __shared__ __bf16 sHid[8 * 64 * HIDST];  // 40 KB per-wave [64 row][32 col]

  const int tid = threadIdx.x, w = tid >> 6, lane = tid & 63;
  const int l15 = lane & 15, lg = lane >> 4;
  const int h = blockIdx.x >> 5, rb = blockIdx.x & 31;

  const __bf16* w0 = W0t + (size_t)h * 32768;
  const __bf16* w1 = W1t + (size_t)h * 16384;
  #pragma unroll
  for (int i = 0; i < 8; ++i) {
    int u = tid + i * 512, row = u >> 4, k8 = (u & 15) << 3;
    *(bf16x8*)&sW0[(row * 128 + k8) ^ SW(row)] = *(const bf16x8*)(w0 + row * 128 + k8);
  }
  #pragma unroll
  for (int i = 0; i < 4; ++i) {
    int u = tid + i * 512, o = u >> 5, k8 = (u & 31) << 3;
    *(bf16x8*)&sW1[(o * 256 + k8) ^ SW(o)] = *(const bf16x8*)(w1 + o * 256 + k8);
  }
  __syncthreads();

  __bf16* myHid = sHid + w * (64 * HIDST);

  #pragma unroll 1
  for (int it = 0; it < 7; ++it) {
    const int roff = it * 512 + w * 64;
    if (roff >= RPB) break;
    const int base = rb * RPB + roff;

    bf16x8 ax[4][4];
    load_ax(coords, base, l15, lg, ax);

    f32x4 acc2[16];
    #pragma unroll
    for (int i = 0; i < 16; ++i) acc2[i] = f32x4{0.f, 0.f, 0.f, 0.f};

    #pragma unroll 1
    for (int c = 0; c < 8; ++c) {
      f32x4 a1[2][4] = {};
      #pragma unroll
      for (int ks = 0; ks < 4; ++ks) {
        bf16x8 wa[2];
        #pragma unroll
        for (int fi = 0; fi < 2; ++fi) {
          int hl = c * 32 + fi * 16 + l15;
          wa[fi] = *(const bf16x8*)&sW0[(hl * 128 + ks * 32 + lg * 8) ^ SW(hl)];
        }
        #pragma unroll
        for (int fi = 0; fi < 2; ++fi)
          #pragma unroll
          for (int jt = 0; jt < 4; ++jt)
            a1[fi][jt] = MFMA16(wa[fi], ax[jt][ks], a1[fi][jt]);
      }
      #pragma unroll
      for (int fi = 0; fi < 2; ++fi) {
        f32x4 b0v = *(const f32x4*)&bq0[h * 256 + c * 32 + fi * 16 + lg * 4];
        #pragma unroll
        for (int jt = 0; jt < 4; ++jt) {
          bf16x4 hv;
          #pragma unroll
          for (int r = 0; r < 4; ++r) {
            float v = a1[fi][jt][r] + b0v[r];
            hv[r] = (__bf16)(v > 0.f ? v : 0.f);
          }
          *(bf16x4*)&myHid[(jt * 16 + l15) * HIDST + fi * 16 + lg * 4] = hv;
        }
      }
      bf16x8 hb[4], wf[4];
      #pragma unroll
      for (int jt = 0; jt < 4; ++jt)
        hb[jt] = *(const bf16x8*)&myHid[(jt * 16 + l15) * HIDST + lg * 8];
      #pragma unroll
      for (int f = 0; f < 4; ++f) {
        int o = f * 16 + l15;
        wf[f] = *(const bf16x8*)&sW1[(o * 256 + c * 32 + lg * 8) ^ SW(o)];
      }
      #pragma unroll
      for (int ft = 0; ft < 4; ++ft)
        #pragma unroll
        for (int jt = 0; jt < 4; ++jt)
          acc2[ft * 4 + jt] = MFMA16(wf[ft], hb[jt], acc2[ft * 4 + jt]);   // swapped
    }

    float mq[4];
    #pragma unroll
    for (int jt = 0; jt < 4; ++jt) {
      int rq = base + jt * 16 + l15;
      mq[jt] = (rq < NPTS) ? mask[rq] : 0.f;
    }
    #pragma unroll
    for (int ft = 0; ft < 4; ++ft) {
      f32x4 b1v = *(const f32x4*)&bq1[h * 64 + ft * 16 + lg * 4];
      #pragma unroll
      for (int jt = 0; jt < 4; ++jt) {
        bf16x4 qv;
        f32x4 a = acc2[ft * 4 + jt];
        #pragma unroll
        for (int r = 0; r < 4; ++r) {
          float v = (a[r] + b1v[r]) * mq[jt];
          qv[r] = (__bf16)(v > 0.f ? v + 1.f : __expf(v));
        }
        *(bf16x4*)(qk_ws + ((size_t)h * NPAD + base + jt * 16 + l15) * 64 + ft * 16 + lg * 4) = qv;
      }
    }
  }
}

// ---------- k/v GEMM over one half of N (50176 rows) ----------
__global__ __launch_bounds__(512, 2) void k_kvgemm(
    const float* __restrict__ coords, const float* __restrict__ mask,
    const __bf16* __restrict__ W0t, const __bf16* __restrict__ W1t,
    const float* __restrict__ bk0, const float* __restrict__ bk1,
    const float* __restrict__ bv0, const float* __restrict__ bv1,
    __bf16* __restrict__ kkTh, __bf16* __restrict__ vTh, int rowOff)
{
  __shared__ __bf16 sW0[32768];
  __shared__ __bf16 sW1[16384];
  __shared__ __bf16 sHid[8 * 64 * HIDST];

  const int tid = threadIdx.x, w = tid >> 6, lane = tid & 63;
  const int l15 = lane & 15, lg = lane >> 4;
  const int mh2 = blockIdx.x >> 4, rb = blockIdx.x & 15;
  const int m2 = mh2 >> 3, h = mh2 & 7;          // m2: 0=k, 1=v

  const __bf16* w0 = W0t + (size_t)((m2 + 1) * 8 + h) * 32768;
  const __bf16* w1 = W1t + (size_t)((m2 + 1) * 8 + h) * 16384;
  #pragma unroll
  for (int i = 0; i < 8; ++i) {
    int u = tid + i * 512, row = u >> 4, k8 = (u & 15) << 3;
    *(bf16x8*)&sW0[(row * 128 + k8) ^ SW(row)] = *(const bf16x8*)(w0 + row * 128 + k8);
  }
  #pragma unroll
  for (int i = 0; i < 4; ++i) {
    int u = tid + i * 512, o = u >> 5, k8 = (u & 31) << 3;
    *(bf16x8*)&sW1[(o * 256 + k8) ^ SW(o)] = *(const bf16x8*)(w1 + o * 256 + k8);
  }
  __syncthreads();

  const float* b0 = m2 ? bv0 : bk0;
  const float* b1 = m2 ? bv1 : bk1;
  __bf16* dstT = m2 ? vTh : kkTh;
  __bf16* myHid = sHid + w * (64 * HIDST);

  #pragma unroll 1
  for (int it = 0; it < 7; ++it) {
    const int roff = it * 512 + w * 64;
    if (roff >= RPB) break;
    const int lbase = rb * RPB + roff;          // half-local
    const int gbase = rowOff + lbase;           // global

    bf16x8 ax[4][4];
    load_ax(coords, gbase, l15, lg, ax);

    f32x4 acc2[16];
    #pragma unroll
    for (int i = 0; i < 16; ++i) acc2[i] = f32x4{0.f, 0.f, 0.f, 0.f};

    #pragma unroll 1
    for (int c = 0; c < 8; ++c) {
      f32x4 a1[2][4] = {};
      #pragma unroll
      for (int ks = 0; ks < 4; ++ks) {
        bf16x8 wa[2];
        #pragma unroll
        for (int fi = 0; fi < 2; ++fi) {
          int hl = c * 32 + fi * 16 + l15;
          wa[fi] = *(const bf16x8*)&sW0[(hl * 128 + ks * 32 + lg * 8) ^ SW(hl)];
        }
        #pragma unroll
        for (int fi = 0; fi < 2; ++fi)
          #pragma unroll
          for (int jt = 0; jt < 4; ++jt)
            a1[fi][jt] = MFMA16(wa[fi], ax[jt][ks], a1[fi][jt]);
      }
      #pragma unroll
      for (int fi = 0; fi < 2; ++fi) {
        f32x4 b0v = *(const f32x4*)&b0[h * 256 + c * 32 + fi * 16 + lg * 4];
        #pragma unroll
        for (int jt = 0; jt < 4; ++jt) {
          bf16x4 hv;
          #pragma unroll
          for (int r = 0; r < 4; ++r) {
            float v = a1[fi][jt][r] + b0v[r];
            hv[r] = (__bf16)(v > 0.f ? v : 0.f);
          }
          *(bf16x4*)&myHid[(jt * 16 + l15) * HIDST + fi * 16 + lg * 4] = hv;
        }
      }
      bf16x8 hb[4], wf[4];
      #pragma unroll
      for (int jt = 0; jt < 4; ++jt)
        hb[jt] = *(const bf16x8*)&myHid[(jt * 16 + l15) * HIDST + lg * 8];
      #pragma unroll
      for (int f = 0; f < 4; ++f) {
        int o = f * 16 + l15;
        wf[f] = *(const bf16x8*)&sW1[(o * 256 + c * 32 + lg * 8) ^ SW(o)];
      }
      #pragma unroll
      for (int jt = 0; jt < 4; ++jt)
        #pragma unroll
        for (int f = 0; f < 4; ++f)
          acc2[jt * 4 + f] = MFMA16(hb[jt], wf[f], acc2[jt * 4 + f]);      // normal
    }

    f32x4 mv[4];
    #pragma unroll
    for (int jt = 0; jt < 4; ++jt) {
      int rv = gbase + jt * 16 + lg * 4;
      #pragma unroll
      for (int r = 0; r < 4; ++r) mv[jt][r] = (rv + r < NPTS) ? mask[rv + r] : 0.f;
    }
    if (m2 == 0) {
      #pragma unroll
      for (int f = 0; f < 4; ++f) {
        float b1s = b1[h * 64 + f * 16 + l15];
        #pragma unroll
        for (int jt = 0; jt < 4; ++jt) {
          bf16x4 k4;
          f32x4 a = acc2[jt * 4 + f];
          #pragma unroll
          for (int r = 0; r < 4; ++r) {
            int row = gbase + jt * 16 + lg * 4 + r;
            float v = (a[r] + b1s) * mv[jt][r];
            k4[r] = (__bf16)((row < NPTS) ? (v > 0.f ? v + 1.f : __expf(v)) : 0.f);
          }
          *(bf16x4*)(dstT + (size_t)(h * 64 + f * 16 + l15) * NHALF + lbase + jt * 16 + lg * 4) = k4;
        }
      }
    } else {
      #pragma unroll
      for (int f = 0; f < 4; ++f) {
        float b1s = b1[h * 64 + f * 16 + l15];
        #pragma unroll
        for (int jt = 0; jt < 4; ++jt) {
          bf16x4 v4;
          f32x4 a = acc2[jt * 4 + f];
          #pragma unroll
          for (int r = 0; r < 4; ++r)
            v4[r] = (__bf16)((a[r] + b1s) * mv[jt][r]);
          *(bf16x4*)(dstT + (size_t)(h * 64 + f * 16 + l15) * NHALF + lbase + jt * 16 + lg * 4) = v4;
        }
      }
    }
  }
}

// ---------- kv = kkT @ v over one half (split-K 1024 rows), sumk via ones-MFMA ----------
__global__ __launch_bounds__(256) void k_kv(
    const __bf16* __restrict__ kkTh, const __bf16* __restrict__ vTh,
    float* __restrict__ parts_kv, float* __restrict__ parts_sk, int poff)
{
  __shared__ __bf16 sA[64 * KVST];
  __shared__ __bf16 sB[64 * KVST];
  const int tid = threadIdx.x, w = tid >> 6, lane = tid & 63;
  const int l15 = lane & 15, lg = lane >> 4;
  const int sp = blockIdx.x, h = blockIdx.y;
  const int kbase0 = sp * 1024;

  bf16x8 ones;
  #pragma unroll
  for (int e = 0; e < 8; ++e) ones[e] = (__bf16)1.0f;

  f32x4 akv[4] = {};
  f32x4 ask = {};

  #pragma unroll 1
  for (int ch = 0; ch < 4; ++ch) {
    int kb = kbase0 + ch * 256;
    __syncthreads();
    #pragma unroll
    for (int i = 0; i < 8; ++i) {
      int u = tid + i * 256, row = u >> 5, k8 = (u & 31) << 3;
      *(bf16x8*)&sA[row * KVST + k8] = *(const bf16x8*)(kkTh + (size_t)(h * 64 + row) * NHALF + kb + k8);
    }
    #pragma unroll
    for (int i = 0; i < 8; ++i) {
      int u = tid + i * 256, row = u >> 5, k8 = (u & 31) << 3;
      *(bf16x8*)&sB[row * KVST + k8] = *(const bf16x8*)(vTh + (size_t)(h * 64 + row) * NHALF + kb + k8);
    }
    __syncthreads();
    #pragma unroll
    for (int ks = 0; ks < 8; ++ks) {
      bf16x8 a = *(const bf16x8*)&sA[(w * 16 + l15) * KVST + ks * 32 + lg * 8];
      #pragma unroll
      for (int fj = 0; fj < 4; ++fj) {
        bf16x8 b = *(const bf16x8*)&sB[(fj * 16 + l15) * KVST + ks * 32 + lg * 8];
        akv[fj] = MFMA16(a, b, akv[fj]);
      }
      ask = MFMA16(a, ones, ask);
    }
  }
  float* dkv = parts_kv + ((size_t)h * 98 + poff + sp) * 4096;
  #pragma unroll
  for (int fj = 0; fj < 4; ++fj)
    #pragma unroll
    for (int r = 0; r < 4; ++r)
      dkv[(size_t)(w * 16 + lg * 4 + r) * 64 + fj * 16 + l15] = akv[fj][r];
  if (l15 == 0) {
    float* dsk = parts_sk + ((size_t)h * 98 + poff + sp) * 64;
    #pragma unroll
    for (int r = 0; r < 4; ++r) dsk[w * 16 + lg * 4 + r] = ask[r];
  }
}

// ---------- reduce parts -> kvTe bf16 [8][j][kq], sumk f32 [512] ----------
__global__ void k_kvt(const float* __restrict__ parts_kv, const float* __restrict__ parts_sk,
                      __bf16* __restrict__ kvTe, float* __restrict__ sumk) {
  int i = blockIdx.x * 256 + threadIdx.x;
  if (i < 32768) {
    int h = i >> 12, rem = i & 4095;
    float s = 0.f;
    for (int sp = 0; sp < 98; ++sp) s += parts_kv[((size_t)h * 98 + sp) * 4096 + rem];
    int kq = rem >> 6, j = rem & 63;
    kvTe[((size_t)h * 64 + j) * 64 + kq] = (__bf16)s;
  } else if (i < 33280) {
    int t = i - 32768;
    int h = t >> 6, c = t & 63;
    float s = 0.f;
    for (int sp = 0; sp < 98; ++sp) s += parts_sk[((size_t)h * 98 + sp) * 64 + c];
    sumk[t] = s;
  }
}

// ---------- attention normalize + psi MLP ----------
// Wave-PAIR split of psi layer1 output cols: each wave owns 16 rows x 128 hid
// cols -> acc1[8] (32 regs) -> fits 128-reg budget at 2 blocks/CU, no spill.
// Pair duplicates the tiny num/den work; layer2 partials pair-reduced via LDS.
__global__ __launch_bounds__(512, 4) void k_cd(
    const float* __restrict__ mask, const __bf16* __restrict__ qk_ws,
    const __bf16* __restrict__ kvTe, const float* __restrict__ sumk,
    const __bf16* __restrict__ Wp0t, const __bf16* __restrict__ Wp1t,
    const float* __restrict__ bp0, const float* __restrict__ bp1,
    float* __restrict__ out)
{
  __shared__ __bf16 sWp0c[16384];          // 32 KB: [256 col][64 k]; reused as f32 pairbuf
  __shared__ __bf16 sCat[8 * 16 * CDST];   // 17 KB: per-wave cat [16][64]
  __shared__ __bf16 sHc[8 * 16 * CDST];    // 17 KB: per-wave hid chunk [16][64]
  __shared__ float sSumk[512];             //  2 KB   -> total ~69 KB, 2 blocks/CU

  const int tid = threadIdx.x, w = tid >> 6, lane = tid & 63, l15 = lane & 15, lg = lane >> 4;
  const int pair = w >> 1, wh = w & 1;     // 4 pairs; wh = which 128-col half
  const int rbase = blockIdx.x * 64 + pair * 16;
  __bf16* myCat = sCat + w * (16 * CDST);
  __bf16* myHc = sHc + w * (16 * CDST);

  sSumk[tid] = sumk[tid];

  // direct Wp0 chunk staging (transient registers only)
  auto STAGEW = [&](int h) {
    #pragma unroll
    for (int i = 0; i < 4; ++i) {
      int u = tid + i * 512;
      int col = u >> 3, koff = (u & 7) << 3;
      *(bf16x8*)&sWp0c[(col * 64 + koff) ^ SW(col)] =
          *(const bf16x8*)(Wp0t + (size_t)col * 512 + h * 64 + koff);
    }
  };

  STAGEW(0);
  __syncthreads();          // covers sSumk + first sWp0c

  f32x4 acc1[8] = {};       // psi layer1: our 128 hid cols x 16 rows
  #pragma unroll 1
  for (int h = 0; h < 8; ++h) {
    bf16x8 axq[2];
    #pragma unroll
    for (int ks = 0; ks < 2; ++ks)
      axq[ks] = *(const bf16x8*)(qk_ws + ((size_t)h * NPAD + rbase + l15) * 64 + ks * 32 + lg * 8);
    // num = qk @ kv (duplicated within pair — 4 MFMAs)
    f32x4 accn[4] = {};
    #pragma unroll
    for (int ks = 0; ks < 2; ++ks)
      #pragma unroll
      for (int f = 0; f < 4; ++f) {
        bf16x8 bv = *(const bf16x8*)(kvTe + ((size_t)h * 64 + f * 16 + l15) * 64 + ks * 32 + lg * 8);
        accn[f] = MFMA16(axq[ks], bv, accn[f]);
      }
    // den
    float p = 0.f;
    #pragma unroll
    for (int ks = 0; ks < 2; ++ks)
      #pragma unroll
      for (int e = 0; e < 8; ++e)
        p += (float)axq[ks][e] * sSumk[h * 64 + ks * 32 + lg * 8 + e];
    p += __shfl_xor(p, 16);
    p += __shfl_xor(p, 32);
    float dinv[4];
    #pragma unroll
    for (int r = 0; r < 4; ++r) {
      float d = __shfl(p, (lane & 48) + ((lane >> 4) << 2) + r);
      d = (d == 0.f) ? 1e-6f : d;
      dinv[r] = 1.f / d;
    }
    // cat chunk -> wave-private LDS
    #pragma unroll
    for (int f = 0; f < 4; ++f)
      #pragma unroll
      for (int r = 0; r < 4; ++r)
        myCat[(lg * 4 + r) * CDST + f * 16 + l15] = (__bf16)(accn[f][r] * dinv[r]);
    // psi layer1 partial: only OUR half of Wp0 cols (wh*128 ..)
    #pragma unroll
    for (int ks2 = 0; ks2 < 2; ++ks2) {
      bf16x8 aC = *(const bf16x8*)&myCat[l15 * CDST + ks2 * 32 + lg * 8];
      #pragma unroll
      for (int f = 0; f < 8; ++f) {
        int col = wh * 128 + f * 16 + l15;   // col&7 == l15&7 -> SW(l15) consistent
        bf16x8 bw = *(const bf16x8*)&sWp0c[(col * 64 + ks2 * 32 + lg * 8) ^ SW(l15)];
        acc1[f] = MFMA16(aC, bw, acc1[f]);
      }
    }
    if (h + 1 < 8) {
      __syncthreads();      // all waves done reading sWp0c for head h
      STAGEW(h + 1);
      __syncthreads();      // ready for head h+1
    }
  }
  __syncthreads();          // sWp0c reads done -> safe to reuse as pairbuf

  // layer2 partial over OUR 128 k (2 chunks of 64), hid wave-private
  f32x4 acc2[8] = {};
  #pragma unroll
  for (int c = 0; c < 2; ++c) {
    #pragma unroll
    for (int fi = 0; fi < 4; ++fi) {
      float bias = bp0[wh * 128 + (c * 4 + fi) * 16 + l15];
      #pragma unroll
      for (int r = 0; r < 4; ++r) {
        float val = acc1[c * 4 + fi][r] + bias;
        val = val > 0.f ? val : 0.f;
        myHc[(lg * 4 + r) * CDST + fi * 16 + l15] = (__bf16)val;
      }
    }
    #pragma unroll
    for (int ks2 = 0; ks2 < 2; ++ks2) {
      bf16x8 aH = *(const bf16x8*)&myHc[l15 * CDST + ks2 * 32 + lg * 8];
      #pragma unroll
      for (int f = 0; f < 8; ++f) {
        bf16x8 bw = *(const bf16x8*)(Wp1t + (size_t)(f * 16 + l15) * 256 + wh * 128 + c * 64 + ks2 * 32 + lg * 8);
        acc2[f] = MFMA16(aH, bw, acc2[f]);
      }
    }
  }
  // pair-reduce acc2 through retired sWp0c (lane-stride-1, conflict-free)
  float* pb = (float*)sWp0c;               // 4 pairs x 2048 floats = 32 KB
  if (wh == 1) {
    #pragma unroll
    for (int f = 0; f < 8; ++f)
      #pragma unroll
      for (int r = 0; r < 4; ++r)
        pb[pair * 2048 + (f * 4 + r) * 64 + lane] = acc2[f][r];
  }
  __syncthreads();
  if (wh == 0) {
    float mvr[4];
    #pragma unroll
    for (int r = 0; r < 4; ++r) {
      int grow = rbase + lg * 4 + r;
      mvr[r] = (grow < NPTS) ? mask[grow] : 0.f;
    }
    #pragma unroll
    for (int f = 0; f < 8; ++f) {
      int col = f * 16 + l15;
      float bias = bp1[col];
      #pragma unroll
      for (int r = 0; r < 4; ++r) {
        int grow = rbase + lg * 4 + r;
        if (grow < NPTS) {
          float val = acc2[f][r] + pb[pair * 2048 + (f * 4 + r) * 64 + lane];
          out[(size_t)grow * 128 + col] = (val + bias) * mvr[r];
        }
      }
    }
  }
}

extern "C" void kernel_launch(void* const* d_in, const int* in_sizes, int n_in,
                              void* d_out, int out_size, void* d_ws, size_t ws_size,
                              hipStream_t stream) {
  const float* coords = (const float*)d_in[0];
  const float* mask   = (const float*)d_in[1];
  const float* Wq0 = (const float*)d_in[2];
  const float* bq0 = (const float*)d_in[3];
  const float* Wq1 = (const float*)d_in[4];
  const float* bq1 = (const float*)d_in[5];
  const float* Wk0 = (const float*)d_in[6];
  const float* bk0 = (const float*)d_in[7];
  const float* Wk1 = (const float*)d_in[8];
  const float* bk1 = (const float*)d_in[9];
  const float* Wv0 = (const float*)d_in[10];
  const float* bv0 = (const float*)d_in[11];
  const float* Wv1 = (const float*)d_in[12];
  const float* bv1 = (const float*)d_in[13];
  const float* Wp0 = (const float*)d_in[14];
  const float* bp0 = (const float*)d_in[15];
  const float* Wp1 = (const float*)d_in[16];
  const float* bp1 = (const float*)d_in[17];
  float* out = (float*)d_out;

  // workspace: region0 (102.8 MB) time-shared between {kkTh|vTh} and qk_ws.
  char* p = (char*)d_ws;
  __bf16* region0  = (__bf16*)p; p += (size_t)8 * NPAD * 64 * 2;    // 102,760,448
  __bf16* qk_ws    = region0;
  __bf16* kkTh     = region0;
  __bf16* vTh      = region0 + (size_t)8 * 64 * NHALF;
  __bf16* W0t      = (__bf16*)p; p += (size_t)24 * 32768 * 2;       //   1,572,864
  __bf16* W1t      = (__bf16*)p; p += (size_t)24 * 16384 * 2;       //     786,432
  __bf16* Wp0t     = (__bf16*)p; p += (size_t)256 * 512 * 2;        //     262,144
  __bf16* Wp1t     = (__bf16*)p; p += (size_t)128 * 256 * 2;        //      65,536
  float*  parts_kv = (float*)p;  p += (size_t)8 * 98 * 4096 * 4;    //  12,845,056
  float*  parts_sk = (float*)p;  p += (size_t)8 * 98 * 64 * 4;      //     200,704
  float*  sumk     = (float*)p;  p += (size_t)512 * 4;              //       2,048
  __bf16* kvTe     = (__bf16*)p; p += (size_t)8 * 64 * 64 * 2;      //      65,536

  k_prep_w<<<1024, 256, 0, stream>>>(Wq0, Wk0, Wv0, Wq1, Wk1, Wv1, Wp0, Wp1,
                                     W0t, W1t, Wp0t, Wp1t);
  k_kvgemm<<<256, 512, 0, stream>>>(coords, mask, W0t, W1t, bk0, bk1, bv0, bv1,
                                    kkTh, vTh, 0);
  k_kv<<<dim3(49, 8), 256, 0, stream>>>(kkTh, vTh, parts_kv, parts_sk, 0);
  k_kvgemm<<<256, 512, 0, stream>>>(coords, mask, W0t, W1t, bk0, bk1, bv0, bv1,
                                    kkTh, vTh, NHALF);
  k_kv<<<dim3(49, 8), 256, 0, stream>>>(kkTh, vTh, parts_kv, parts_sk, 49);
  k_qgemm<<<256, 512, 0, stream>>>(coords, mask, W0t, W1t, bq0, bq1, qk_ws);
  k_kvt<<<130, 256, 0, stream>>>(parts_kv, parts_sk, kvTe, sumk);
  k_cd<<<1568, 512, 0, stream>>>(mask, qk_ws, kvTe, sumk, Wp0t, Wp1t, bp0, bp1, out);
}

// Round 15
// 553.554 us; speedup vs baseline: 1.6460x; 1.1532x over previous
//
#include <hip/hip_runtime.h>
#include <hip/hip_bf16.h>
#include <math.h>

// N=100000, D=128, H=8, HID=256, QK=64, V=64, PSI_HID=256, OUT=128
#define NPTS 100000
#define NPAD 100352           // 784*128 = 32*3136 = 1568*64 = 392*256 = 196*512
#define NHALF 50176           // 16*3136 = 49*1024
#define RPB 3136              // rows per gemm block
#define HIDST 40              // per-wave hid row stride (80 B)
#define KVST 264              // k_kv LDS row stride

typedef __bf16 bf16x8 __attribute__((ext_vector_type(8)));
typedef __bf16 bf16x4 __attribute__((ext_vector_type(4)));
typedef float f32x4 __attribute__((ext_vector_type(4)));

#define MFMA16(a,b,c) __builtin_amdgcn_mfma_f32_16x16x32_bf16((a),(b),(c),0,0,0)
#define SW(row) (((row)&7)<<3)

// ---------- prep: weights cast/transpose ----------
__global__ void k_prep_w(const float* __restrict__ Wq0, const float* __restrict__ Wk0,
                         const float* __restrict__ Wv0, const float* __restrict__ Wq1,
                         const float* __restrict__ Wk1, const float* __restrict__ Wv1,
                         const float* __restrict__ Wp0, const float* __restrict__ Wp1,
                         __bf16* __restrict__ W0t, __bf16* __restrict__ W1t,
                         __bf16* __restrict__ Wp0t, __bf16* __restrict__ Wp1t) {
  for (int i = blockIdx.x * 256 + threadIdx.x; i < 1343488; i += gridDim.x * 256) {
    if (i < 786432) {                      // W0t [24][256 hid][128 d]
      int g = i >> 15, j = i & 32767;
      int mat = g >> 3, h = g & 7, mcol = j >> 7, k = j & 127;
      const float* src = (mat == 0) ? Wq0 : (mat == 1) ? Wk0 : Wv0;
      W0t[i] = (__bf16)src[h * 32768 + k * 256 + mcol];
    } else if (i < 1179648) {              // W1t [24][64 o][256 hid]
      int t = i - 786432;
      int g = t >> 14, j = t & 16383;
      int mat = g >> 3, h = g & 7, ocol = j >> 8, k = j & 255;
      const float* src = (mat == 0) ? Wq1 : (mat == 1) ? Wk1 : Wv1;
      W1t[t] = (__bf16)src[h * 16384 + k * 64 + ocol];
    } else if (i < 1310720) {              // Wp0t [256 col][512 k]
      int t = i - 1179648;
      int col = t >> 9, k = t & 511;
      Wp0t[t] = (__bf16)Wp0[k * 256 + col];
    } else {                               // Wp1t [128 o][256 k]
      int t = i - 1310720;
      int col = t >> 8, k = t & 255;
      Wp1t[t] = (__bf16)Wp1[k * 128 + col];
    }
  }
}

// ---------- load 64 X rows (f32 -> bf16 regs), zero beyond NPTS ----------
__device__ __forceinline__ void load_ax(const float* __restrict__ coords,
                                        int base, int l15, int lg, bf16x8 (&ax)[4][4]) {
  #pragma unroll
  for (int jt = 0; jt < 4; ++jt) {
    int row = base + jt * 16 + l15;
    bool ok = row < NPTS;
    #pragma unroll
    for (int ks = 0; ks < 4; ++ks) {
      bf16x8 v = {};
      if (ok) {
        const float4* p4 = (const float4*)(coords + (size_t)row * 128 + ks * 32 + lg * 8);
        float4 f0 = p4[0], f1 = p4[1];
        v[0] = (__bf16)f0.x; v[1] = (__bf16)f0.y; v[2] = (__bf16)f0.z; v[3] = (__bf16)f0.w;
        v[4] = (__bf16)f1.x; v[5] = (__bf16)f1.y; v[6] = (__bf16)f1.z; v[7] = (__bf16)f1.w;
      }
      ax[jt][ks] = v;
    }
  }
}

// ---------- q GEMM: one head per 32-block group, 3136 rows/block ----------
__global__ __launch_bounds__(512, 2) void k_qgemm(
    const float* __restrict__ coords, const float* __restrict__ mask,
    const __bf16* __restrict__ W0t, const __bf16* __restrict__ W1t,
    const float* __restrict__ bq0, const float* __restrict__ bq1,
    __bf16* __restrict__ qk_ws)
{
  __shared__ __bf16 sW0[32768];            // 64 KB [256 hid][128 d] swizzled
  __shared__ __bf16 sW1[16384];            // 32 KB [64 o][256 hid] swizzled
  __shared__ __bf16 sHid[8 * 64 * HIDST];  // 40 KB per-wave [64 row][32 col]

  const int tid = threadIdx.x, w = tid >> 6, lane = tid & 63;
  const int l15 = lane & 15, lg = lane >> 4;
  const int h = blockIdx.x >> 5, rb = blockIdx.x & 31;

  const __bf16* w0 = W0t + (size_t)h * 32768;
  const __bf16* w1 = W1t + (size_t)h * 16384;
  #pragma unroll
  for (int i = 0; i < 8; ++i) {
    int u = tid + i * 512, row = u >> 4, k8 = (u & 15) << 3;
    *(bf16x8*)&sW0[(row * 128 + k8) ^ SW(row)] = *(const bf16x8*)(w0 + row * 128 + k8);
  }
  #pragma unroll
  for (int i = 0; i < 4; ++i) {
    int u = tid + i * 512, o = u >> 5, k8 = (u & 31) << 3;
    *(bf16x8*)&sW1[(o * 256 + k8) ^ SW(o)] = *(const bf16x8*)(w1 + o * 256 + k8);
  }
  __syncthreads();

  __bf16* myHid = sHid + w * (64 * HIDST);

  #pragma unroll 1
  for (int it = 0; it < 7; ++it) {
    const int roff = it * 512 + w * 64;
    if (roff >= RPB) break;
    const int base = rb * RPB + roff;

    bf16x8 ax[4][4];
    load_ax(coords, base, l15, lg, ax);

    f32x4 acc2[16];
    #pragma unroll
    for (int i = 0; i < 16; ++i) acc2[i] = f32x4{0.f, 0.f, 0.f, 0.f};

    #pragma unroll 1
    for (int c = 0; c < 8; ++c) {
      f32x4 a1[2][4] = {};
      #pragma unroll
      for (int ks = 0; ks < 4; ++ks) {
        bf16x8 wa[2];
        #pragma unroll
        for (int fi = 0; fi < 2; ++fi) {
          int hl = c * 32 + fi * 16 + l15;
          wa[fi] = *(const bf16x8*)&sW0[(hl * 128 + ks * 32 + lg * 8) ^ SW(hl)];
        }
        #pragma unroll
        for (int fi = 0; fi < 2; ++fi)
          #pragma unroll
          for (int jt = 0; jt < 4; ++jt)
            a1[fi][jt] = MFMA16(wa[fi], ax[jt][ks], a1[fi][jt]);
      }
      #pragma unroll
      for (int fi = 0; fi < 2; ++fi) {
        f32x4 b0v = *(const f32x4*)&bq0[h * 256 + c * 32 + fi * 16 + lg * 4];
        #pragma unroll
        for (int jt = 0; jt < 4; ++jt) {
          bf16x4 hv;
          #pragma unroll
          for (int r = 0; r < 4; ++r) {
            float v = a1[fi][jt][r] + b0v[r];
            hv[r] = (__bf16)(v > 0.f ? v : 0.f);
          }
          *(bf16x4*)&myHid[(jt * 16 + l15) * HIDST + fi * 16 + lg * 4] = hv;
        }
      }
      bf16x8 hb[4], wf[4];
      #pragma unroll
      for (int jt = 0; jt < 4; ++jt)
        hb[jt] = *(const bf16x8*)&myHid[(jt * 16 + l15) * HIDST + lg * 8];
      #pragma unroll
      for (int f = 0; f < 4; ++f) {
        int o = f * 16 + l15;
        wf[f] = *(const bf16x8*)&sW1[(o * 256 + c * 32 + lg * 8) ^ SW(o)];
      }
      #pragma unroll
      for (int ft = 0; ft < 4; ++ft)
        #pragma unroll
        for (int jt = 0; jt < 4; ++jt)
          acc2[ft * 4 + jt] = MFMA16(wf[ft], hb[jt], acc2[ft * 4 + jt]);   // swapped
    }

    float mq[4];
    #pragma unroll
    for (int jt = 0; jt < 4; ++jt) {
      int rq = base + jt * 16 + l15;
      mq[jt] = (rq < NPTS) ? mask[rq] : 0.f;
    }
    #pragma unroll
    for (int ft = 0; ft < 4; ++ft) {
      f32x4 b1v = *(const f32x4*)&bq1[h * 64 + ft * 16 + lg * 4];
      #pragma unroll
      for (int jt = 0; jt < 4; ++jt) {
        bf16x4 qv;
        f32x4 a = acc2[ft * 4 + jt];
        #pragma unroll
        for (int r = 0; r < 4; ++r) {
          float v = (a[r] + b1v[r]) * mq[jt];
          qv[r] = (__bf16)(v > 0.f ? v + 1.f : __expf(v));
        }
        *(bf16x4*)(qk_ws + ((size_t)h * NPAD + base + jt * 16 + l15) * 64 + ft * 16 + lg * 4) = qv;
      }
    }
  }
}

// ---------- k/v GEMM over one half of N (50176 rows) ----------
__global__ __launch_bounds__(512, 2) void k_kvgemm(
    const float* __restrict__ coords, const float* __restrict__ mask,
    const __bf16* __restrict__ W0t, const __bf16* __restrict__ W1t,
    const float* __restrict__ bk0, const float* __restrict__ bk1,
    const float* __restrict__ bv0, const float* __restrict__ bv1,
    __bf16* __restrict__ kkTh, __bf16* __restrict__ vTh, int rowOff)
{
  __shared__ __bf16 sW0[32768];
  __shared__ __bf16 sW1[16384];
  __shared__ __bf16 sHid[8 * 64 * HIDST];

  const int tid = threadIdx.x, w = tid >> 6, lane = tid & 63;
  const int l15 = lane & 15, lg = lane >> 4;
  const int mh2 = blockIdx.x >> 4, rb = blockIdx.x & 15;
  const int m2 = mh2 >> 3, h = mh2 & 7;          // m2: 0=k, 1=v

  const __bf16* w0 = W0t + (size_t)((m2 + 1) * 8 + h) * 32768;
  const __bf16* w1 = W1t + (size_t)((m2 + 1) * 8 + h) * 16384;
  #pragma unroll
  for (int i = 0; i < 8; ++i) {
    int u = tid + i * 512, row = u >> 4, k8 = (u & 15) << 3;
    *(bf16x8*)&sW0[(row * 128 + k8) ^ SW(row)] = *(const bf16x8*)(w0 + row * 128 + k8);
  }
  #pragma unroll
  for (int i = 0; i < 4; ++i) {
    int u = tid + i * 512, o = u >> 5, k8 = (u & 31) << 3;
    *(bf16x8*)&sW1[(o * 256 + k8) ^ SW(o)] = *(const bf16x8*)(w1 + o * 256 + k8);
  }
  __syncthreads();

  const float* b0 = m2 ? bv0 : bk0;
  const float* b1 = m2 ? bv1 : bk1;
  __bf16* dstT = m2 ? vTh : kkTh;
  __bf16* myHid = sHid + w * (64 * HIDST);

  #pragma unroll 1
  for (int it = 0; it < 7; ++it) {
    const int roff = it * 512 + w * 64;
    if (roff >= RPB) break;
    const int lbase = rb * RPB + roff;          // half-local
    const int gbase = rowOff + lbase;           // global

    bf16x8 ax[4][4];
    load_ax(coords, gbase, l15, lg, ax);

    f32x4 acc2[16];
    #pragma unroll
    for (int i = 0; i < 16; ++i) acc2[i] = f32x4{0.f, 0.f, 0.f, 0.f};

    #pragma unroll 1
    for (int c = 0; c < 8; ++c) {
      f32x4 a1[2][4] = {};
      #pragma unroll
      for (int ks = 0; ks < 4; ++ks) {
        bf16x8 wa[2];
        #pragma unroll
        for (int fi = 0; fi < 2; ++fi) {
          int hl = c * 32 + fi * 16 + l15;
          wa[fi] = *(const bf16x8*)&sW0[(hl * 128 + ks * 32 + lg * 8) ^ SW(hl)];
        }
        #pragma unroll
        for (int fi = 0; fi < 2; ++fi)
          #pragma unroll
          for (int jt = 0; jt < 4; ++jt)
            a1[fi][jt] = MFMA16(wa[fi], ax[jt][ks], a1[fi][jt]);
      }
      #pragma unroll
      for (int fi = 0; fi < 2; ++fi) {
        f32x4 b0v = *(const f32x4*)&b0[h * 256 + c * 32 + fi * 16 + lg * 4];
        #pragma unroll
        for (int jt = 0; jt < 4; ++jt) {
          bf16x4 hv;
          #pragma unroll
          for (int r = 0; r < 4; ++r) {
            float v = a1[fi][jt][r] + b0v[r];
            hv[r] = (__bf16)(v > 0.f ? v : 0.f);
          }
          *(bf16x4*)&myHid[(jt * 16 + l15) * HIDST + fi * 16 + lg * 4] = hv;
        }
      }
      bf16x8 hb[4], wf[4];
      #pragma unroll
      for (int jt = 0; jt < 4; ++jt)
        hb[jt] = *(const bf16x8*)&myHid[(jt * 16 + l15) * HIDST + lg * 8];
      #pragma unroll
      for (int f = 0; f < 4; ++f) {
        int o = f * 16 + l15;
        wf[f] = *(const bf16x8*)&sW1[(o * 256 + c * 32 + lg * 8) ^ SW(o)];
      }
      #pragma unroll
      for (int jt = 0; jt < 4; ++jt)
        #pragma unroll
        for (int f = 0; f < 4; ++f)
          acc2[jt * 4 + f] = MFMA16(hb[jt], wf[f], acc2[jt * 4 + f]);      // normal
    }

    f32x4 mv[4];
    #pragma unroll
    for (int jt = 0; jt < 4; ++jt) {
      int rv = gbase + jt * 16 + lg * 4;
      #pragma unroll
      for (int r = 0; r < 4; ++r) mv[jt][r] = (rv + r < NPTS) ? mask[rv + r] : 0.f;
    }
    if (m2 == 0) {
      #pragma unroll
      for (int f = 0; f < 4; ++f) {
        float b1s = b1[h * 64 + f * 16 + l15];
        #pragma unroll
        for (int jt = 0; jt < 4; ++jt) {
          bf16x4 k4;
          f32x4 a = acc2[jt * 4 + f];
          #pragma unroll
          for (int r = 0; r < 4; ++r) {
            int row = gbase + jt * 16 + lg * 4 + r;
            float v = (a[r] + b1s) * mv[jt][r];
            k4[r] = (__bf16)((row < NPTS) ? (v > 0.f ? v + 1.f : __expf(v)) : 0.f);
          }
          *(bf16x4*)(dstT + (size_t)(h * 64 + f * 16 + l15) * NHALF + lbase + jt * 16 + lg * 4) = k4;
        }
      }
    } else {
      #pragma unroll
      for (int f = 0; f < 4; ++f) {
        float b1s = b1[h * 64 + f * 16 + l15];
        #pragma unroll
        for (int jt = 0; jt < 4; ++jt) {
          bf16x4 v4;
          f32x4 a = acc2[jt * 4 + f];
          #pragma unroll
          for (int r = 0; r < 4; ++r)
            v4[r] = (__bf16)((a[r] + b1s) * mv[jt][r]);
          *(bf16x4*)(dstT + (size_t)(h * 64 + f * 16 + l15) * NHALF + lbase + jt * 16 + lg * 4) = v4;
        }
      }
    }
  }
}

// ---------- kv = kkT @ v over one half (split-K 1024 rows), sumk via ones-MFMA ----------
__global__ __launch_bounds__(256) void k_kv(
    const __bf16* __restrict__ kkTh, const __bf16* __restrict__ vTh,
    float* __restrict__ parts_kv, float* __restrict__ parts_sk, int poff)
{
  __shared__ __bf16 sA[64 * KVST];
  __shared__ __bf16 sB[64 * KVST];
  const int tid = threadIdx.x, w = tid >> 6, lane = tid & 63;
  const int l15 = lane & 15, lg = lane >> 4;
  const int sp = blockIdx.x, h = blockIdx.y;
  const int kbase0 = sp * 1024;

  bf16x8 ones;
  #pragma unroll
  for (int e = 0; e < 8; ++e) ones[e] = (__bf16)1.0f;

  f32x4 akv[4] = {};
  f32x4 ask = {};

  #pragma unroll 1
  for (int ch = 0; ch < 4; ++ch) {
    int kb = kbase0 + ch * 256;
    __syncthreads();
    #pragma unroll
    for (int i = 0; i < 8; ++i) {
      int u = tid + i * 256, row = u >> 5, k8 = (u & 31) << 3;
      *(bf16x8*)&sA[row * KVST + k8] = *(const bf16x8*)(kkTh + (size_t)(h * 64 + row) * NHALF + kb + k8);
    }
    #pragma unroll
    for (int i = 0; i < 8; ++i) {
      int u = tid + i * 256, row = u >> 5, k8 = (u & 31) << 3;
      *(bf16x8*)&sB[row * KVST + k8] = *(const bf16x8*)(vTh + (size_t)(h * 64 + row) * NHALF + kb + k8);
    }
    __syncthreads();
    #pragma unroll
    for (int ks = 0; ks < 8; ++ks) {
      bf16x8 a = *(const bf16x8*)&sA[(w * 16 + l15) * KVST + ks * 32 + lg * 8];
      #pragma unroll
      for (int fj = 0; fj < 4; ++fj) {
        bf16x8 b = *(const bf16x8*)&sB[(fj * 16 + l15) * KVST + ks * 32 + lg * 8];
        akv[fj] = MFMA16(a, b, akv[fj]);
      }
      ask = MFMA16(a, ones, ask);
    }
  }
  float* dkv = parts_kv + ((size_t)h * 98 + poff + sp) * 4096;
  #pragma unroll
  for (int fj = 0; fj < 4; ++fj)
    #pragma unroll
    for (int r = 0; r < 4; ++r)
      dkv[(size_t)(w * 16 + lg * 4 + r) * 64 + fj * 16 + l15] = akv[fj][r];
  if (l15 == 0) {
    float* dsk = parts_sk + ((size_t)h * 98 + poff + sp) * 64;
    #pragma unroll
    for (int r = 0; r < 4; ++r) dsk[w * 16 + lg * 4 + r] = ask[r];
  }
}

// ---------- reduce parts -> kvTe bf16 [8][j][kq], sumk f32 [512] ----------
__global__ void k_kvt(const float* __restrict__ parts_kv, const float* __restrict__ parts_sk,
                      __bf16* __restrict__ kvTe, float* __restrict__ sumk) {
  int i = blockIdx.x * 256 + threadIdx.x;
  if (i < 32768) {
    int h = i >> 12, rem = i & 4095;
    float s = 0.f;
    for (int sp = 0; sp < 98; ++sp) s += parts_kv[((size_t)h * 98 + sp) * 4096 + rem];
    int kq = rem >> 6, j = rem & 63;
    kvTe[((size_t)h * 64 + j) * 64 + kq] = (__bf16)s;
  } else if (i < 33280) {
    int t = i - 32768;
    int h = t >> 6, c = t & 63;
    float s = 0.f;
    for (int sp = 0; sp < 98; ++sp) s += parts_sk[((size_t)h * 98 + sp) * 64 + c];
    sumk[t] = s;
  }
}

// ---------- normalize qk in place: cat[h][row][64] = num/den ----------
// Barrier-free, no LDS. Swapped MFMA -> packed bf16x4 writes. Each (h,row)
// owned by exactly one wave; in-place safe (reads complete before stores).
__global__ __launch_bounds__(256, 4) void k_num(
    const __bf16* __restrict__ kvTe, const float* __restrict__ sumk,
    __bf16* __restrict__ qk)
{
  const int tid = threadIdx.x, w = tid >> 6, lane = tid & 63;
  const int l15 = lane & 15, lg = lane >> 4;
  const int h = blockIdx.y;
  const int row = blockIdx.x * 64 + w * 16 + l15;

  bf16x8 axq[2];
  #pragma unroll
  for (int ks = 0; ks < 2; ++ks)
    axq[ks] = *(const bf16x8*)(qk + ((size_t)h * NPAD + row) * 64 + ks * 32 + lg * 8);

  // den for row (l15): per-lane partial + xor over lg groups
  float p = 0.f;
  #pragma unroll
  for (int ks = 0; ks < 2; ++ks) {
    f32x4 sa = *(const f32x4*)&sumk[h * 64 + ks * 32 + lg * 8];
    f32x4 sb = *(const f32x4*)&sumk[h * 64 + ks * 32 + lg * 8 + 4];
    #pragma unroll
    for (int e = 0; e < 4; ++e) {
      p += (float)axq[ks][e] * sa[e];
      p += (float)axq[ks][e + 4] * sb[e];
    }
  }
  p += __shfl_xor(p, 16);
  p += __shfl_xor(p, 32);
  float dinv = 1.f / ((p == 0.f) ? 1e-6f : p);

  // num swapped: A = kv (rows = j), B = qk (cols = x-row) -> D[n=l15=row][m=j]
  f32x4 accn[4] = {};
  #pragma unroll
  for (int ks = 0; ks < 2; ++ks)
    #pragma unroll
    for (int f = 0; f < 4; ++f) {
      bf16x8 kvf = *(const bf16x8*)(kvTe + ((size_t)h * 64 + f * 16 + l15) * 64 + ks * 32 + lg * 8);
      accn[f] = MFMA16(kvf, axq[ks], accn[f]);
    }
  // write back packed: cat[row][j = f*16 + lg*4 + r]
  #pragma unroll
  for (int f = 0; f < 4; ++f) {
    bf16x4 cv;
    #pragma unroll
    for (int r = 0; r < 4; ++r) cv[r] = (__bf16)(accn[f][r] * dinv);
    *(bf16x4*)(qk + ((size_t)h * NPAD + row) * 64 + f * 16 + lg * 4) = cv;
  }
}

// ---------- psi layer1: h2 = relu(cat @ Wp0 + bp0), col-half per block ----------
// Wp0 half (128 KB) staged ONCE; barrier-free row loop; 64 rows/wave;
// swapped MFMA -> packed bf16x4 h2 writes.
__global__ __launch_bounds__(512, 2) void k_psi1(
    const __bf16* __restrict__ cat, const __bf16* __restrict__ Wp0t,
    const float* __restrict__ bp0, __bf16* __restrict__ h2)
{
  __shared__ __bf16 sW[65536];   // 128 KB: [128 col][512 k] swizzled

  const int tid = threadIdx.x, w = tid >> 6, lane = tid & 63;
  const int l15 = lane & 15, lg = lane >> 4;
  const int wh = blockIdx.x & 1, rc = blockIdx.x >> 1;
  const int rbase = rc * 512 + w * 64;

  #pragma unroll
  for (int i = 0; i < 16; ++i) {
    int u = tid + i * 512;               // 0..8191
    int col = u >> 6, g = u & 63;
    *(bf16x8*)&sW[(col * 512 + g * 8) ^ SW(col)] =
        *(const bf16x8*)(Wp0t + (size_t)(wh * 128 + col) * 512 + g * 8);
  }
  __syncthreads();

  f32x4 acc[32];                          // [f*4 + jt], all static indices
  #pragma unroll
  for (int i = 0; i < 32; ++i) acc[i] = f32x4{0.f, 0.f, 0.f, 0.f};

  #pragma unroll 1
  for (int ks = 0; ks < 16; ++ks) {       // K chunks of 32 (h = ks>>1)
    bf16x8 ca[4];
    #pragma unroll
    for (int jt = 0; jt < 4; ++jt)
      ca[jt] = *(const bf16x8*)(cat + ((size_t)(ks >> 1) * NPAD + rbase + jt * 16 + l15) * 64
                                + (ks & 1) * 32 + lg * 8);
    #pragma unroll
    for (int f = 0; f < 8; ++f) {
      int col = f * 16 + l15;
      bf16x8 wf = *(const bf16x8*)&sW[(col * 512 + ks * 32 + lg * 8) ^ SW(col)];
      #pragma unroll
      for (int jt = 0; jt < 4; ++jt)
        acc[f * 4 + jt] = MFMA16(wf, ca[jt], acc[f * 4 + jt]);   // swapped
    }
  }
  // bias + relu -> h2 [row][256], packed bf16x4 at col = wh*128 + f*16 + lg*4
  #pragma unroll
  for (int f = 0; f < 8; ++f) {
    f32x4 bv = *(const f32x4*)&bp0[wh * 128 + f * 16 + lg * 4];
    #pragma unroll
    for (int jt = 0; jt < 4; ++jt) {
      bf16x4 hv;
      f32x4 a = acc[f * 4 + jt];
      #pragma unroll
      for (int r = 0; r < 4; ++r) {
        float v = a[r] + bv[r];
        hv[r] = (__bf16)(v > 0.f ? v : 0.f);
      }
      *(bf16x4*)(h2 + (size_t)(rbase + jt * 16 + l15) * 256 + wh * 128 + f * 16 + lg * 4) = hv;
    }
  }
}

// ---------- psi layer2: out = (h2 @ Wp1 + bp1) * mask ----------
// Wp1 (64 KB) staged ONCE; barrier-free; 32 rows/wave; swapped -> f32x4 writes.
__global__ __launch_bounds__(512, 4) void k_psi2(
    const float* __restrict__ mask, const __bf16* __restrict__ h2,
    const __bf16* __restrict__ Wp1t, const float* __restrict__ bp1,
    float* __restrict__ out)
{
  __shared__ __bf16 sW[32768];   // 64 KB: [128 o][256 k] swizzled

  const int tid = threadIdx.x, w = tid >> 6, lane = tid & 63;
  const int l15 = lane & 15, lg = lane >> 4;
  const int rbase = blockIdx.x * 256 + w * 32;

  #pragma unroll
  for (int i = 0; i < 8; ++i) {
    int u = tid + i * 512;               // 0..4095
    int o = u >> 5, g = u & 31;
    *(bf16x8*)&sW[(o * 256 + g * 8) ^ SW(o)] =
        *(const bf16x8*)(Wp1t + (size_t)o * 256 + g * 8);
  }
  __syncthreads();

  f32x4 acc[16];                          // [f*2 + jt]
  #pragma unroll
  for (int i = 0; i < 16; ++i) acc[i] = f32x4{0.f, 0.f, 0.f, 0.f};

  #pragma unroll 1
  for (int ks = 0; ks < 8; ++ks) {        // K=256 in chunks of 32
    bf16x8 ha[2];
    #pragma unroll
    for (int jt = 0; jt < 2; ++jt)
      ha[jt] = *(const bf16x8*)(h2 + (size_t)(rbase + jt * 16 + l15) * 256 + ks * 32 + lg * 8);
    #pragma unroll
    for (int f = 0; f < 8; ++f) {
      int o = f * 16 + l15;
      bf16x8 wf = *(const bf16x8*)&sW[(o * 256 + ks * 32 + lg * 8) ^ SW(o)];
      #pragma unroll
      for (int jt = 0; jt < 2; ++jt)
        acc[f * 2 + jt] = MFMA16(wf, ha[jt], acc[f * 2 + jt]);   // swapped
    }
  }
  float mq[2];
  #pragma unroll
  for (int jt = 0; jt < 2; ++jt) {
    int row = rbase + jt * 16 + l15;
    mq[jt] = (row < NPTS) ? mask[row] : 0.f;
  }
  #pragma unroll
  for (int f = 0; f < 8; ++f) {
    f32x4 bv = *(const f32x4*)&bp1[f * 16 + lg * 4];
    #pragma unroll
    for (int jt = 0; jt < 2; ++jt) {
      int row = rbase + jt * 16 + l15;
      if (row < NPTS) {
        f32x4 ov;
        f32x4 a = acc[f * 2 + jt];
        #pragma unroll
        for (int r = 0; r < 4; ++r) ov[r] = (a[r] + bv[r]) * mq[jt];
        *(f32x4*)(out + (size_t)row * 128 + f * 16 + lg * 4) = ov;
      }
    }
  }
}

extern "C" void kernel_launch(void* const* d_in, const int* in_sizes, int n_in,
                              void* d_out, int out_size, void* d_ws, size_t ws_size,
                              hipStream_t stream) {
  const float* coords = (const float*)d_in[0];
  const float* mask   = (const float*)d_in[1];
  const float* Wq0 = (const float*)d_in[2];
  const float* bq0 = (const float*)d_in[3];
  const float* Wq1 = (const float*)d_in[4];
  const float* bq1 = (const float*)d_in[5];
  const float* Wk0 = (const float*)d_in[6];
  const float* bk0 = (const float*)d_in[7];
  const float* Wk1 = (const float*)d_in[8];
  const float* bk1 = (const float*)d_in[9];
  const float* Wv0 = (const float*)d_in[10];
  const float* bv0 = (const float*)d_in[11];
  const float* Wv1 = (const float*)d_in[12];
  const float* bv1 = (const float*)d_in[13];
  const float* Wp0 = (const float*)d_in[14];
  const float* bp0 = (const float*)d_in[15];
  const float* Wp1 = (const float*)d_in[16];
  const float* bp1 = (const float*)d_in[17];
  float* out = (float*)d_out;

  // workspace (~170 MB): region0 time-shared {kkTh|vTh} -> qk_ws -> cat (in place)
  char* p = (char*)d_ws;
  __bf16* region0  = (__bf16*)p; p += (size_t)8 * NPAD * 64 * 2;    // 102,760,448
  __bf16* qk_ws    = region0;
  __bf16* kkTh     = region0;
  __bf16* vTh      = region0 + (size_t)8 * 64 * NHALF;
  __bf16* W0t      = (__bf16*)p; p += (size_t)24 * 32768 * 2;       //   1,572,864
  __bf16* W1t      = (__bf16*)p; p += (size_t)24 * 16384 * 2;       //     786,432
  __bf16* Wp0t     = (__bf16*)p; p += (size_t)256 * 512 * 2;        //     262,144
  __bf16* Wp1t     = (__bf16*)p; p += (size_t)128 * 256 * 2;        //      65,536
  float*  parts_kv = (float*)p;  p += (size_t)8 * 98 * 4096 * 4;    //  12,845,056
  float*  parts_sk = (float*)p;  p += (size_t)8 * 98 * 64 * 4;      //     200,704
  float*  sumk     = (float*)p;  p += (size_t)512 * 4;              //       2,048
  __bf16* kvTe     = (__bf16*)p; p += (size_t)8 * 64 * 64 * 2;      //      65,536
  __bf16* h2       = (__bf16*)p; p += (size_t)NPAD * 256 * 2;       //  51,380,224

  k_prep_w<<<1024, 256, 0, stream>>>(Wq0, Wk0, Wv0, Wq1, Wk1, Wv1, Wp0, Wp1,
                                     W0t, W1t, Wp0t, Wp1t);
  k_kvgemm<<<256, 512, 0, stream>>>(coords, mask, W0t, W1t, bk0, bk1, bv0, bv1,
                                    kkTh, vTh, 0);
  k_kv<<<dim3(49, 8), 256, 0, stream>>>(kkTh, vTh, parts_kv, parts_sk, 0);
  k_kvgemm<<<256, 512, 0, stream>>>(coords, mask, W0t, W1t, bk0, bk1, bv0, bv1,
                                    kkTh, vTh, NHALF);
  k_kv<<<dim3(49, 8), 256, 0, stream>>>(kkTh, vTh, parts_kv, parts_sk, 49);
  k_qgemm<<<256, 512, 0, stream>>>(coords, mask, W0t, W1t, bq0, bq1, qk_ws);
  k_kvt<<<130, 256, 0, stream>>>(parts_kv, parts_sk, kvTe, sumk);
  k_num<<<dim3(1568, 8), 256, 0, stream>>>(kvTe, sumk, qk_ws);
  k_psi1<<<392, 512, 0, stream>>>(qk_ws, Wp0t, bp0, h2);
  k_psi2<<<392, 512, 0, stream>>>(mask, h2, Wp1t, bp1, out);
}